// Round 1
// baseline (1460.374 us; speedup 1.0000x reference)
//
#include <hip/hip_runtime.h>

#define NB 16
#define NP 2048
#define HD 128
#define LDP 136   // padded LDS row (bf16 elems): 272B = 17*16B -> even bank spread for ds_read_b128

typedef __bf16 bf16_t;
typedef bf16_t bf16x8 __attribute__((ext_vector_type(8)));
typedef bf16_t bf16x4 __attribute__((ext_vector_type(4)));
typedef float  f32x4  __attribute__((ext_vector_type(4)));

// ---------------- top-8 insertion helpers (fully unrolled, register-resident) ----------------
__device__ __forceinline__ void ins8_min(float key, int j, float bd[8], int bi[8]) {
  float c = key; int cj = j;
#pragma unroll
  for (int m = 0; m < 8; ++m) {
    bool sm = c < bd[m];                 // strict: earlier j wins ties
    float tb = bd[m]; int ti = bi[m];
    if (sm) { bd[m] = c; bi[m] = cj; c = tb; cj = ti; }
  }
}

__device__ __forceinline__ void ins8_max(float key, int j, float bd[8], int bi[8]) {
  float c = key; int cj = j;
#pragma unroll
  for (int m = 0; m < 8; ++m) {
    bool sm = c > bd[m];
    float tb = bd[m]; int ti = bi[m];
    if (sm) { bd[m] = c; bi[m] = cj; c = tb; cj = ti; }
  }
}

__device__ __forceinline__ void ins8_maxtie(float key, int j, float bd[8], int bi[8]) {
  float c = key; int cj = j;
#pragma unroll
  for (int m = 0; m < 8; ++m) {
    bool sm = (c > bd[m]) || (c == bd[m] && cj < bi[m]);  // tie -> lower index (matches lax.top_k)
    float tb = bd[m]; int ti = bi[m];
    if (sm) { bd[m] = c; bi[m] = cj; c = tb; cj = ti; }
  }
}

// ---------------- weight prep: build transposed bf16 weight mats ----------------
// m=0: W2T1  m=1: WpT2  m=2: WqT2  m=3: W2T2  m=4: WpT3  m=5: WqT3  m=6: W2T3
__global__ __launch_bounds__(256) void wprep_kernel(
    const float* __restrict__ c1W2, const float* __restrict__ c2W1, const float* __restrict__ c2W2,
    const float* __restrict__ c3W1, const float* __restrict__ c3W2,
    bf16_t* __restrict__ W2T1, bf16_t* __restrict__ WpT2, bf16_t* __restrict__ WqT2,
    bf16_t* __restrict__ W2T2, bf16_t* __restrict__ WpT3, bf16_t* __restrict__ WqT3,
    bf16_t* __restrict__ W2T3)
{
  int tid = blockIdx.x * 256 + threadIdx.x;     // < 7*16384
  int m = tid >> 14, e = tid & 16383;
  int r = e >> 7, c = e & 127;                  // out[r*128+c], r = out-channel (n), c = k/d
  switch (m) {
    case 0: W2T1[r*128+c] = (bf16_t)c1W2[c*128+r]; break;
    case 1: WpT2[r*128+c] = (bf16_t)(c2W1[c*128+r] - c2W1[(128+c)*128+r]); break;
    case 2: WqT2[r*128+c] = (bf16_t)c2W1[(128+c)*128+r]; break;
    case 3: W2T2[r*128+c] = (bf16_t)c2W2[c*128+r]; break;
    case 4: WpT3[r*128+c] = (bf16_t)(c3W1[c*128+r] - c3W1[(128+c)*128+r]); break;
    case 5: WqT3[r*128+c] = (bf16_t)c3W1[(128+c)*128+r]; break;
    case 6: W2T3[r*128+c] = (bf16_t)c3W2[c*128+r]; break;
  }
}

// ---------------- layer-1 P/Q (D=3, fp32 pointwise) ----------------
// P[i][c] = sum_d x_d*(W1[d][c]-W1[3+d][c]) + b1[c] ;  Q[j][c] = sum_d x_d*W1[3+d][c]
__global__ __launch_bounds__(256) void pq1_kernel(
    const float* __restrict__ x, const float* __restrict__ W1, const float* __restrict__ b1,
    float* __restrict__ P, float* __restrict__ Q)
{
  int tid = blockIdx.x * 256 + threadIdx.x;     // < 32768*32
  int row = tid >> 5, c0 = (tid & 31) * 4;
  float x0 = x[row*3+0], x1 = x[row*3+1], x2 = x[row*3+2];
#pragma unroll
  for (int u = 0; u < 4; ++u) {
    int c = c0 + u;
    float wq0 = W1[3*128+c], wq1 = W1[4*128+c], wq2 = W1[5*128+c];
    float wp0 = W1[0*128+c]-wq0, wp1 = W1[1*128+c]-wq1, wp2 = W1[2*128+c]-wq2;
    P[(size_t)row*HD + c] = x0*wp0 + x1*wp1 + x2*wp2 + b1[c];
    Q[(size_t)row*HD + c] = x0*wq0 + x1*wq1 + x2*wq2;
  }
}

// ---------------- kNN layer 1 (D=3, fp32 brute force, exact) ----------------
__global__ __launch_bounds__(64) void knn1_kernel(const float* __restrict__ x, int* __restrict__ idxo)
{
  int t = blockIdx.x * 64 + threadIdx.x;        // < 32768
  int b = t >> 11, i = t & (NP - 1);
  const float* xb = x + (size_t)b * NP * 3;
  float xi0 = xb[i*3+0], xi1 = xb[i*3+1], xi2 = xb[i*3+2];
  float bd[8]; int bi[8];
#pragma unroll
  for (int m = 0; m < 8; ++m) { bd[m] = 3.0e38f; bi[m] = 0x7fffffff; }
  for (int j = 0; j < NP; ++j) {
    float a0 = xb[j*3+0], a1 = xb[j*3+1], a2 = xb[j*3+2];
    // key = d2 - |xi|^2 (row-constant dropped): monotone in d2
    float key = (a0*a0 + a1*a1 + a2*a2) - 2.0f*(a0*xi0 + a1*xi1 + a2*xi2);
    if (key < bd[7]) ins8_min(key, j, bd, bi);
  }
  int* o = idxo + (size_t)t * 8;
#pragma unroll
  for (int m = 0; m < 8; ++m) o[m] = bi[m];
}

// ---------------- bf16 row norms ----------------
__global__ __launch_bounds__(256) void prep_sq_kernel(const bf16_t* __restrict__ X, float* __restrict__ sqg)
{
  int r = blockIdx.x * 256 + threadIdx.x;       // < 32768
  const bf16_t* row = X + (size_t)r * HD;
  float s = 0.f;
#pragma unroll
  for (int c = 0; c < HD; c += 8) {
    bf16x8 v = *(const bf16x8*)&row[c];
#pragma unroll
    for (int q = 0; q < 8; ++q) { float f = (float)v[q]; s += f * f; }
  }
  sqg[r] = s;
}

// ---------------- P/Q GEMM for layers 2/3: X(bf16)[32768x128] @ WT^T -> fp32 ----------------
__global__ __launch_bounds__(256) void pq_gemm_kernel(
    const bf16_t* __restrict__ X, const bf16_t* __restrict__ WpT, const bf16_t* __restrict__ WqT,
    const float* __restrict__ b1, float* __restrict__ P, float* __restrict__ Q)
{
  __shared__ __align__(16) bf16_t At[128 * LDP];
  const int r0 = blockIdx.x * 128;
  const bool isP = (blockIdx.y == 0);
  const bf16_t* __restrict__ WT = isP ? WpT : WqT;
  float* __restrict__ Out = isP ? P : Q;
  const int t = threadIdx.x;
  for (int u = t; u < 2048; u += 256) {
    int r = u >> 4, c = (u & 15) * 8;
    *(bf16x8*)&At[r*LDP + c] = *(const bf16x8*)&X[(size_t)(r0 + r)*HD + c];
  }
  __syncthreads();
  const int lane = t & 63, w = t >> 6, quad = lane >> 4, l16 = lane & 15;
  f32x4 acc[2][8];
  f32x4 z = {0.f, 0.f, 0.f, 0.f};
#pragma unroll
  for (int rt = 0; rt < 2; ++rt)
#pragma unroll
    for (int ct = 0; ct < 8; ++ct) acc[rt][ct] = z;
#pragma unroll
  for (int ks = 0; ks < 4; ++ks) {
    const int kk = ks*32 + quad*8;
    bf16x8 a0 = *(const bf16x8*)&At[(w*32 + l16)*LDP + kk];
    bf16x8 a1 = *(const bf16x8*)&At[(w*32 + 16 + l16)*LDP + kk];
#pragma unroll
    for (int ct = 0; ct < 8; ++ct) {
      bf16x8 bb = *(const bf16x8*)&WT[(ct*16 + l16)*HD + kk];   // L2-hot, 32KB matrix
      acc[0][ct] = __builtin_amdgcn_mfma_f32_16x16x32_bf16(a0, bb, acc[0][ct], 0, 0, 0);
      acc[1][ct] = __builtin_amdgcn_mfma_f32_16x16x32_bf16(a1, bb, acc[1][ct], 0, 0, 0);
    }
  }
#pragma unroll
  for (int rt = 0; rt < 2; ++rt)
#pragma unroll
    for (int ct = 0; ct < 8; ++ct) {
      float bv = isP ? b1[ct*16 + l16] : 0.f;
#pragma unroll
      for (int r = 0; r < 4; ++r) {
        int row = w*32 + rt*16 + quad*4 + r;
        Out[(size_t)(r0 + row)*HD + ct*16 + l16] = acc[rt][ct][r] + bv;
      }
    }
}

// ---------------- fused Gram(MFMA) + top-8 select for layers 2/3 ----------------
// block: (istrip of 64 rows, batch). maximize key_j = 2*<xi,xj> - |xj|^2  (== sqi - d2)
__global__ __launch_bounds__(256) void knn_big_kernel(
    const bf16_t* __restrict__ X, const float* __restrict__ sqg, int* __restrict__ idxo)
{
  __shared__ __align__(16) bf16_t Ai[64 * LDP];
  __shared__ __align__(16) bf16_t Xj[64 * LDP];
  __shared__ float keys[64 * 65];               // reused at the end as merge scratch
  const int b = blockIdx.y, i0 = blockIdx.x * 64;
  const int t = threadIdx.x;
  const bf16_t* __restrict__ Xb = X + (size_t)b * NP * HD;
  for (int u = t; u < 1024; u += 256) {
    int r = u >> 4, c = (u & 15) * 8;
    *(bf16x8*)&Ai[r*LDP + c] = *(const bf16x8*)&Xb[(size_t)(i0 + r)*HD + c];
  }
  const int lane = t & 63, w = t >> 6, quad = lane >> 4, l16 = lane & 15;
  const int selr = t >> 2, selp = t & 3;
  float tk[8]; int tj[8];
#pragma unroll
  for (int m = 0; m < 8; ++m) { tk[m] = -3.0e38f; tj[m] = 0x7fffffff; }
  __syncthreads();
  bf16x8 af[4];
#pragma unroll
  for (int ks = 0; ks < 4; ++ks)
    af[ks] = *(const bf16x8*)&Ai[(w*16 + l16)*LDP + ks*32 + quad*8];
  f32x4 z = {0.f, 0.f, 0.f, 0.f};

  for (int jt = 0; jt < 32; ++jt) {
    const int j0 = jt * 64;
    __syncthreads();                            // prev select done reading keys / prev MFMA done with Xj
    for (int u = t; u < 1024; u += 256) {
      int r = u >> 4, c = (u & 15) * 8;
      *(bf16x8*)&Xj[r*LDP + c] = *(const bf16x8*)&Xb[(size_t)(j0 + r)*HD + c];
    }
    __syncthreads();
    f32x4 acc[4] = {z, z, z, z};
#pragma unroll
    for (int ks = 0; ks < 4; ++ks) {
      const int kk = ks*32 + quad*8;
#pragma unroll
      for (int ct = 0; ct < 4; ++ct) {
        bf16x8 bb = *(const bf16x8*)&Xj[(ct*16 + l16)*LDP + kk];
        acc[ct] = __builtin_amdgcn_mfma_f32_16x16x32_bf16(af[ks], bb, acc[ct], 0, 0, 0);
      }
    }
#pragma unroll
    for (int ct = 0; ct < 4; ++ct) {
      float sqv = sqg[(size_t)b*NP + j0 + ct*16 + l16];
#pragma unroll
      for (int r = 0; r < 4; ++r)
        keys[(w*16 + quad*4 + r)*65 + ct*16 + l16] = 2.f*acc[ct][r] - sqv;
    }
    __syncthreads();
    // selection: 4 threads per row, each owns a 16-col partition of this tile
#pragma unroll
    for (int c = 0; c < 16; ++c) {
      float key = keys[selr*65 + selp*16 + c];
      int j = j0 + selp*16 + c;
      if (key > tk[7]) ins8_max(key, j, tk, tj);
    }
  }
  __syncthreads();                              // last select done; reuse keys[] as merge scratch
  float* ck = keys;                             // 2048 floats
  int*   cj = (int*)(keys + 2048);              // 2048 ints (fits: keys has 4160 slots)
#pragma unroll
  for (int m = 0; m < 8; ++m) { ck[selr*32 + selp*8 + m] = tk[m]; cj[selr*32 + selp*8 + m] = tj[m]; }
  __syncthreads();
  if (t < 64) {
    float bk[8]; int bj[8];
#pragma unroll
    for (int m = 0; m < 8; ++m) { bk[m] = -3.0e38f; bj[m] = 0x7fffffff; }
    for (int m = 0; m < 32; ++m) {
      float key = ck[t*32 + m]; int j = cj[t*32 + m];
      if (key > bk[7] || (key == bk[7] && j < bj[7])) ins8_maxtie(key, j, bk, bj);
    }
    int* o = idxo + ((size_t)b*NP + i0 + t) * 8;
#pragma unroll
    for (int m = 0; m < 8; ++m) o[m] = bj[m];
  }
}

// ---------------- edge MLP: h1=relu(P_i+Q_j) tile -> MFMA @ W2T -> bias/relu -> mean8 ----------------
__global__ __launch_bounds__(256) void edge_mlp_kernel(
    const float* __restrict__ P, const float* __restrict__ Q, const int* __restrict__ idx,
    const bf16_t* __restrict__ W2T, const float* __restrict__ b2,
    bf16_t* __restrict__ xout, float* __restrict__ pooled, int poolOff)
{
  __shared__ __align__(16) bf16_t At[128 * LDP];
  __shared__ float Mn[16 * 128];
  const int b = blockIdx.y, i0 = blockIdx.x * 16;
  const int t = threadIdx.x;
  {
    const int e = t >> 1, half = t & 1;         // 128 edge rows, 2 threads/row
    const int i = i0 + (e >> 3);
    const int j = idx[((size_t)b*NP + i)*8 + (e & 7)];
    const float4* Pr = (const float4*)(P + ((size_t)b*NP + i)*HD);
    const float4* Qr = (const float4*)(Q + ((size_t)b*NP + j)*HD);
#pragma unroll
    for (int c4 = half*16; c4 < half*16 + 16; ++c4) {
      float4 pv = Pr[c4], qv = Qr[c4];
      bf16x4 h;
      h[0] = (bf16_t)fmaxf(pv.x + qv.x, 0.f);
      h[1] = (bf16_t)fmaxf(pv.y + qv.y, 0.f);
      h[2] = (bf16_t)fmaxf(pv.z + qv.z, 0.f);
      h[3] = (bf16_t)fmaxf(pv.w + qv.w, 0.f);
      *(bf16x4*)&At[e*LDP + c4*4] = h;
    }
  }
  __syncthreads();
  const int lane = t & 63, w = t >> 6, quad = lane >> 4, l16 = lane & 15;
  f32x4 acc[2][8];
  f32x4 z = {0.f, 0.f, 0.f, 0.f};
#pragma unroll
  for (int rt = 0; rt < 2; ++rt)
#pragma unroll
    for (int ct = 0; ct < 8; ++ct) acc[rt][ct] = z;
#pragma unroll
  for (int ks = 0; ks < 4; ++ks) {
    const int kk = ks*32 + quad*8;
    bf16x8 a0 = *(const bf16x8*)&At[(w*32 + l16)*LDP + kk];
    bf16x8 a1 = *(const bf16x8*)&At[(w*32 + 16 + l16)*LDP + kk];
#pragma unroll
    for (int ct = 0; ct < 8; ++ct) {
      bf16x8 bb = *(const bf16x8*)&W2T[(ct*16 + l16)*HD + kk];
      acc[0][ct] = __builtin_amdgcn_mfma_f32_16x16x32_bf16(a0, bb, acc[0][ct], 0, 0, 0);
      acc[1][ct] = __builtin_amdgcn_mfma_f32_16x16x32_bf16(a1, bb, acc[1][ct], 0, 0, 0);
    }
  }
  // bias + relu + mean over 8 edge-rows (rows quad*4+r; quad-pair combine via shfl_xor 16)
#pragma unroll
  for (int rt = 0; rt < 2; ++rt)
#pragma unroll
    for (int ct = 0; ct < 8; ++ct) {
      float bv = b2[ct*16 + l16];
      float s = 0.f;
#pragma unroll
      for (int r = 0; r < 4; ++r) s += fmaxf(acc[rt][ct][r] + bv, 0.f);
      s += __shfl_xor(s, 16);
      if ((quad & 1) == 0) {
        int pt = w*4 + rt*2 + (quad >> 1);
        Mn[pt*128 + ct*16 + l16] = s * 0.125f;
      }
    }
  __syncthreads();
  for (int u = t; u < 2048; u += 256) {
    int pt = u >> 7, c = u & 127;
    xout[((size_t)b*NP + i0 + pt)*HD + c] = (bf16_t)Mn[u];
  }
  if (t < 128) {
    float ss = 0.f;
#pragma unroll
    for (int pt = 0; pt < 16; ++pt) ss += Mn[pt*128 + t];
    atomicAdd(&pooled[b*384 + poolOff + t], ss);
  }
}

// ---------------- final pooled MLP ----------------
__global__ __launch_bounds__(128) void final_mlp_kernel(
    const float* __restrict__ pooled, const float* __restrict__ W1, const float* __restrict__ b1v,
    const float* __restrict__ W2, const float* __restrict__ b2v, float* __restrict__ out)
{
  __shared__ float hb[128];
  int b = blockIdx.x, g = threadIdx.x;
  float h = b1v[g];
  const float inv = 1.0f / (float)NP;
  for (int c = 0; c < 384; ++c) h += pooled[b*384 + c] * inv * W1[c*128 + g];
  hb[g] = fmaxf(h, 0.f);
  __syncthreads();
  if (g < 2) {
    float o = b2v[g];
    for (int k2 = 0; k2 < 128; ++k2) o += hb[k2] * W2[k2*2 + g];
    out[b*2 + g] = o;
  }
}

extern "C" void kernel_launch(void* const* d_in, const int* in_sizes, int n_in,
                              void* d_out, int out_size, void* d_ws, size_t ws_size,
                              hipStream_t stream) {
  (void)in_sizes; (void)n_in; (void)out_size; (void)ws_size;
  const float* x    = (const float*)d_in[0];
  const float* c1W1 = (const float*)d_in[1];
  const float* c1b1 = (const float*)d_in[2];
  const float* c1W2 = (const float*)d_in[3];
  const float* c1b2 = (const float*)d_in[4];
  const float* c2W1 = (const float*)d_in[5];
  const float* c2b1 = (const float*)d_in[6];
  const float* c2W2 = (const float*)d_in[7];
  const float* c2b2 = (const float*)d_in[8];
  const float* c3W1 = (const float*)d_in[9];
  const float* c3b1 = (const float*)d_in[10];
  const float* c3W2 = (const float*)d_in[11];
  const float* c3b2 = (const float*)d_in[12];
  const float* mW1  = (const float*)d_in[13];
  const float* mb1  = (const float*)d_in[14];
  const float* mW2  = (const float*)d_in[15];
  const float* mb2  = (const float*)d_in[16];

  char* wsp = (char*)d_ws;
  auto carve = [&](size_t bytes) -> void* {
    void* p = (void*)wsp; wsp += (bytes + 255) & ~(size_t)255; return p;
  };
  bf16_t* x1b  = (bf16_t*)carve((size_t)NB*NP*HD*2);
  bf16_t* x2b  = (bf16_t*)carve((size_t)NB*NP*HD*2);
  bf16_t* x3b  = (bf16_t*)carve((size_t)NB*NP*HD*2);
  float*  Pbuf = (float*)carve((size_t)NB*NP*HD*4);
  float*  Qbuf = (float*)carve((size_t)NB*NP*HD*4);
  float*  sqb  = (float*)carve((size_t)NB*NP*4);
  int*    idxb = (int*)carve((size_t)NB*NP*8*4);
  bf16_t* W2T1 = (bf16_t*)carve(128*128*2);
  bf16_t* WpT2 = (bf16_t*)carve(128*128*2);
  bf16_t* WqT2 = (bf16_t*)carve(128*128*2);
  bf16_t* W2T2 = (bf16_t*)carve(128*128*2);
  bf16_t* WpT3 = (bf16_t*)carve(128*128*2);
  bf16_t* WqT3 = (bf16_t*)carve(128*128*2);
  bf16_t* W2T3 = (bf16_t*)carve(128*128*2);
  float*  pooled = (float*)carve((size_t)NB*384*4);

  hipMemsetAsync(pooled, 0, (size_t)NB*384*4, stream);
  wprep_kernel<<<448, 256, 0, stream>>>(c1W2, c2W1, c2W2, c3W1, c3W2,
                                        W2T1, WpT2, WqT2, W2T2, WpT3, WqT3, W2T3);
  // layer 1
  pq1_kernel<<<4096, 256, 0, stream>>>(x, c1W1, c1b1, Pbuf, Qbuf);
  knn1_kernel<<<512, 64, 0, stream>>>(x, idxb);
  edge_mlp_kernel<<<dim3(NP/16, NB), 256, 0, stream>>>(Pbuf, Qbuf, idxb, W2T1, c1b2, x1b, pooled, 0);
  // layer 2
  prep_sq_kernel<<<128, 256, 0, stream>>>(x1b, sqb);
  pq_gemm_kernel<<<dim3(NB*NP/128, 2), 256, 0, stream>>>(x1b, WpT2, WqT2, c2b1, Pbuf, Qbuf);
  knn_big_kernel<<<dim3(NP/64, NB), 256, 0, stream>>>(x1b, sqb, idxb);
  edge_mlp_kernel<<<dim3(NP/16, NB), 256, 0, stream>>>(Pbuf, Qbuf, idxb, W2T2, c2b2, x2b, pooled, 128);
  // layer 3
  prep_sq_kernel<<<128, 256, 0, stream>>>(x2b, sqb);
  pq_gemm_kernel<<<dim3(NB*NP/128, 2), 256, 0, stream>>>(x2b, WpT3, WqT3, c3b1, Pbuf, Qbuf);
  knn_big_kernel<<<dim3(NP/64, NB), 256, 0, stream>>>(x2b, sqb, idxb);
  edge_mlp_kernel<<<dim3(NP/16, NB), 256, 0, stream>>>(Pbuf, Qbuf, idxb, W2T3, c3b2, x3b, pooled, 256);
  // head
  final_mlp_kernel<<<NB, 128, 0, stream>>>(pooled, mW1, mb1, mW2, mb2, (float*)d_out);
}

// Round 2
// 1165.644 us; speedup vs baseline: 1.2528x; 1.2528x over previous
//
#include <hip/hip_runtime.h>

#define NB 16
#define NP 2048
#define HD 128
#define LDP 136   // padded LDS row (bf16 elems): 272B = 17*16B -> even bank spread for ds_read_b128

typedef __bf16 bf16_t;
typedef bf16_t bf16x8 __attribute__((ext_vector_type(8)));
typedef bf16_t bf16x4 __attribute__((ext_vector_type(4)));
typedef float  f32x4  __attribute__((ext_vector_type(4)));

// ---------------- top-8 insertion helpers (fully unrolled, register-resident) ----------------
__device__ __forceinline__ void ins8_min(float key, int j, float bd[8], int bi[8]) {
  float c = key; int cj = j;
#pragma unroll
  for (int m = 0; m < 8; ++m) {
    bool sm = c < bd[m];                 // strict: earlier j wins ties
    float tb = bd[m]; int ti = bi[m];
    if (sm) { bd[m] = c; bi[m] = cj; c = tb; cj = ti; }
  }
}

__device__ __forceinline__ void ins8_mintie(float key, int j, float bd[8], int bi[8]) {
  float c = key; int cj = j;
#pragma unroll
  for (int m = 0; m < 8; ++m) {
    bool sm = (c < bd[m]) || (c == bd[m] && cj < bi[m]);  // tie -> lower index (matches lax.top_k)
    float tb = bd[m]; int ti = bi[m];
    if (sm) { bd[m] = c; bi[m] = cj; c = tb; cj = ti; }
  }
}

__device__ __forceinline__ void ins8_max(float key, int j, float bd[8], int bi[8]) {
  float c = key; int cj = j;
#pragma unroll
  for (int m = 0; m < 8; ++m) {
    bool sm = c > bd[m];
    float tb = bd[m]; int ti = bi[m];
    if (sm) { bd[m] = c; bi[m] = cj; c = tb; cj = ti; }
  }
}

__device__ __forceinline__ void ins8_maxtie(float key, int j, float bd[8], int bi[8]) {
  float c = key; int cj = j;
#pragma unroll
  for (int m = 0; m < 8; ++m) {
    bool sm = (c > bd[m]) || (c == bd[m] && cj < bi[m]);  // tie -> lower index (matches lax.top_k)
    float tb = bd[m]; int ti = bi[m];
    if (sm) { bd[m] = c; bi[m] = cj; c = tb; cj = ti; }
  }
}

// ---------------- weight prep: build transposed bf16 weight mats ----------------
// m=0: W2T1  m=1: WpT2  m=2: WqT2  m=3: W2T2  m=4: WpT3  m=5: WqT3  m=6: W2T3
__global__ __launch_bounds__(256) void wprep_kernel(
    const float* __restrict__ c1W2, const float* __restrict__ c2W1, const float* __restrict__ c2W2,
    const float* __restrict__ c3W1, const float* __restrict__ c3W2,
    bf16_t* __restrict__ W2T1, bf16_t* __restrict__ WpT2, bf16_t* __restrict__ WqT2,
    bf16_t* __restrict__ W2T2, bf16_t* __restrict__ WpT3, bf16_t* __restrict__ WqT3,
    bf16_t* __restrict__ W2T3)
{
  int tid = blockIdx.x * 256 + threadIdx.x;     // < 7*16384
  int m = tid >> 14, e = tid & 16383;
  int r = e >> 7, c = e & 127;                  // out[r*128+c], r = out-channel (n), c = k/d
  switch (m) {
    case 0: W2T1[r*128+c] = (bf16_t)c1W2[c*128+r]; break;
    case 1: WpT2[r*128+c] = (bf16_t)(c2W1[c*128+r] - c2W1[(128+c)*128+r]); break;
    case 2: WqT2[r*128+c] = (bf16_t)c2W1[(128+c)*128+r]; break;
    case 3: W2T2[r*128+c] = (bf16_t)c2W2[c*128+r]; break;
    case 4: WpT3[r*128+c] = (bf16_t)(c3W1[c*128+r] - c3W1[(128+c)*128+r]); break;
    case 5: WqT3[r*128+c] = (bf16_t)c3W1[(128+c)*128+r]; break;
    case 6: W2T3[r*128+c] = (bf16_t)c3W2[c*128+r]; break;
  }
}

// ---------------- layer-1 P/Q (D=3, fp32 pointwise) ----------------
// P[i][c] = sum_d x_d*(W1[d][c]-W1[3+d][c]) + b1[c] ;  Q[j][c] = sum_d x_d*W1[3+d][c]
__global__ __launch_bounds__(256) void pq1_kernel(
    const float* __restrict__ x, const float* __restrict__ W1, const float* __restrict__ b1,
    float* __restrict__ P, float* __restrict__ Q)
{
  int tid = blockIdx.x * 256 + threadIdx.x;     // < 32768*32
  int row = tid >> 5, c0 = (tid & 31) * 4;
  float x0 = x[row*3+0], x1 = x[row*3+1], x2 = x[row*3+2];
#pragma unroll
  for (int u = 0; u < 4; ++u) {
    int c = c0 + u;
    float wq0 = W1[3*128+c], wq1 = W1[4*128+c], wq2 = W1[5*128+c];
    float wp0 = W1[0*128+c]-wq0, wp1 = W1[1*128+c]-wq1, wp2 = W1[2*128+c]-wq2;
    P[(size_t)row*HD + c] = x0*wp0 + x1*wp1 + x2*wp2 + b1[c];
    Q[(size_t)row*HD + c] = x0*wq0 + x1*wq1 + x2*wq2;
  }
}

// ---------------- kNN layer 1 (D=3, LDS-staged, 4 j-partitions per point) ----------------
// key_j = |xj|^2 - 2<xi,xj>  (monotone in d2; same formula as validated round-1 kernel)
__global__ __launch_bounds__(256) void knn1_kernel(const float* __restrict__ x, int* __restrict__ idxo)
{
  __shared__ __align__(16) float4 pts[NP];      // 32 KB: (x, y, z, |x|^2)
  __shared__ float ck[64 * 32];                 // 8 KB merge scratch
  __shared__ int   cjs[64 * 32];                // 8 KB
  const int b = blockIdx.y, i0 = blockIdx.x * 64;
  const int t = threadIdx.x;
  const float* __restrict__ xb = x + (size_t)b * NP * 3;
  for (int u = t; u < NP; u += 256) {
    float a0 = xb[u*3+0], a1 = xb[u*3+1], a2 = xb[u*3+2];
    pts[u] = make_float4(a0, a1, a2, a0*a0 + a1*a1 + a2*a2);
  }
  __syncthreads();
  const int selr = t >> 2, selp = t & 3;        // 64 rows x 4 partitions
  const float4 pi = pts[i0 + selr];
  float bd[8]; int bi[8];
#pragma unroll
  for (int m = 0; m < 8; ++m) { bd[m] = 3.0e38f; bi[m] = 0x7fffffff; }
  // interleaved partitions: j = 4*jj + selp -> the 4 lane addresses are contiguous
  // 16B blocks (conflict-free broadcast across the wave's 16 row-groups)
#pragma unroll 8
  for (int jj = 0; jj < NP / 4; ++jj) {
    int j = jj * 4 + selp;
    float4 p = pts[j];
    float key = p.w - 2.0f * (p.x*pi.x + p.y*pi.y + p.z*pi.z);
    if (key < bd[7]) ins8_min(key, j, bd, bi);
  }
#pragma unroll
  for (int m = 0; m < 8; ++m) { ck[selr*32 + selp*8 + m] = bd[m]; cjs[selr*32 + selp*8 + m] = bi[m]; }
  __syncthreads();
  if (t < 64) {
    float bk[8]; int bj[8];
#pragma unroll
    for (int m = 0; m < 8; ++m) { bk[m] = 3.0e38f; bj[m] = 0x7fffffff; }
    for (int m = 0; m < 32; ++m) {
      float key = ck[t*32 + m]; int j = cjs[t*32 + m];
      if (key < bk[7] || (key == bk[7] && j < bj[7])) ins8_mintie(key, j, bk, bj);
    }
    int* o = idxo + ((size_t)b*NP + i0 + t) * 8;
#pragma unroll
    for (int m = 0; m < 8; ++m) o[m] = bj[m];
  }
}

// ---------------- bf16 row norms ----------------
__global__ __launch_bounds__(256) void prep_sq_kernel(const bf16_t* __restrict__ X, float* __restrict__ sqg)
{
  int r = blockIdx.x * 256 + threadIdx.x;       // < 32768
  const bf16_t* row = X + (size_t)r * HD;
  float s = 0.f;
#pragma unroll
  for (int c = 0; c < HD; c += 8) {
    bf16x8 v = *(const bf16x8*)&row[c];
#pragma unroll
    for (int q = 0; q < 8; ++q) { float f = (float)v[q]; s += f * f; }
  }
  sqg[r] = s;
}

// ---------------- P/Q GEMM for layers 2/3: X(bf16)[32768x128] @ WT^T -> fp32 ----------------
__global__ __launch_bounds__(256) void pq_gemm_kernel(
    const bf16_t* __restrict__ X, const bf16_t* __restrict__ WpT, const bf16_t* __restrict__ WqT,
    const float* __restrict__ b1, float* __restrict__ P, float* __restrict__ Q)
{
  __shared__ __align__(16) bf16_t At[128 * LDP];
  const int r0 = blockIdx.x * 128;
  const bool isP = (blockIdx.y == 0);
  const bf16_t* __restrict__ WT = isP ? WpT : WqT;
  float* __restrict__ Out = isP ? P : Q;
  const int t = threadIdx.x;
  for (int u = t; u < 2048; u += 256) {
    int r = u >> 4, c = (u & 15) * 8;
    *(bf16x8*)&At[r*LDP + c] = *(const bf16x8*)&X[(size_t)(r0 + r)*HD + c];
  }
  __syncthreads();
  const int lane = t & 63, w = t >> 6, quad = lane >> 4, l16 = lane & 15;
  f32x4 acc[2][8];
  f32x4 z = {0.f, 0.f, 0.f, 0.f};
#pragma unroll
  for (int rt = 0; rt < 2; ++rt)
#pragma unroll
    for (int ct = 0; ct < 8; ++ct) acc[rt][ct] = z;
#pragma unroll
  for (int ks = 0; ks < 4; ++ks) {
    const int kk = ks*32 + quad*8;
    bf16x8 a0 = *(const bf16x8*)&At[(w*32 + l16)*LDP + kk];
    bf16x8 a1 = *(const bf16x8*)&At[(w*32 + 16 + l16)*LDP + kk];
#pragma unroll
    for (int ct = 0; ct < 8; ++ct) {
      bf16x8 bb = *(const bf16x8*)&WT[(ct*16 + l16)*HD + kk];   // L2-hot, 32KB matrix
      acc[0][ct] = __builtin_amdgcn_mfma_f32_16x16x32_bf16(a0, bb, acc[0][ct], 0, 0, 0);
      acc[1][ct] = __builtin_amdgcn_mfma_f32_16x16x32_bf16(a1, bb, acc[1][ct], 0, 0, 0);
    }
  }
#pragma unroll
  for (int rt = 0; rt < 2; ++rt)
#pragma unroll
    for (int ct = 0; ct < 8; ++ct) {
      float bv = isP ? b1[ct*16 + l16] : 0.f;
#pragma unroll
      for (int r = 0; r < 4; ++r) {
        int row = w*32 + rt*16 + quad*4 + r;
        Out[(size_t)(r0 + row)*HD + ct*16 + l16] = acc[rt][ct][r] + bv;
      }
    }
}

// ---------------- fused Gram(MFMA) + top-8 select for layers 2/3 ----------------
// block: (istrip of 64 rows, batch). maximize key_j = 2*<xi,xj> - |xj|^2  (== sqi - d2)
__global__ __launch_bounds__(256) void knn_big_kernel(
    const bf16_t* __restrict__ X, const float* __restrict__ sqg, int* __restrict__ idxo)
{
  __shared__ __align__(16) bf16_t Ai[64 * LDP];
  __shared__ __align__(16) bf16_t Xj[64 * LDP];
  __shared__ float keys[64 * 65];               // reused at the end as merge scratch
  const int b = blockIdx.y, i0 = blockIdx.x * 64;
  const int t = threadIdx.x;
  const bf16_t* __restrict__ Xb = X + (size_t)b * NP * HD;
  for (int u = t; u < 1024; u += 256) {
    int r = u >> 4, c = (u & 15) * 8;
    *(bf16x8*)&Ai[r*LDP + c] = *(const bf16x8*)&Xb[(size_t)(i0 + r)*HD + c];
  }
  const int lane = t & 63, w = t >> 6, quad = lane >> 4, l16 = lane & 15;
  const int selr = t >> 2, selp = t & 3;
  float tk[8]; int tj[8];
#pragma unroll
  for (int m = 0; m < 8; ++m) { tk[m] = -3.0e38f; tj[m] = 0x7fffffff; }
  __syncthreads();
  bf16x8 af[4];
#pragma unroll
  for (int ks = 0; ks < 4; ++ks)
    af[ks] = *(const bf16x8*)&Ai[(w*16 + l16)*LDP + ks*32 + quad*8];
  f32x4 z = {0.f, 0.f, 0.f, 0.f};

  for (int jt = 0; jt < 32; ++jt) {
    const int j0 = jt * 64;
    __syncthreads();                            // prev select done reading keys / prev MFMA done with Xj
    for (int u = t; u < 1024; u += 256) {
      int r = u >> 4, c = (u & 15) * 8;
      *(bf16x8*)&Xj[r*LDP + c] = *(const bf16x8*)&Xb[(size_t)(j0 + r)*HD + c];
    }
    __syncthreads();
    f32x4 acc[4] = {z, z, z, z};
#pragma unroll
    for (int ks = 0; ks < 4; ++ks) {
      const int kk = ks*32 + quad*8;
#pragma unroll
      for (int ct = 0; ct < 4; ++ct) {
        bf16x8 bb = *(const bf16x8*)&Xj[(ct*16 + l16)*LDP + kk];
        acc[ct] = __builtin_amdgcn_mfma_f32_16x16x32_bf16(af[ks], bb, acc[ct], 0, 0, 0);
      }
    }
#pragma unroll
    for (int ct = 0; ct < 4; ++ct) {
      float sqv = sqg[(size_t)b*NP + j0 + ct*16 + l16];
#pragma unroll
      for (int r = 0; r < 4; ++r)
        keys[(w*16 + quad*4 + r)*65 + ct*16 + l16] = 2.f*acc[ct][r] - sqv;
    }
    __syncthreads();
    // selection: 4 threads per row, each owns a 16-col partition of this tile
#pragma unroll
    for (int c = 0; c < 16; ++c) {
      float key = keys[selr*65 + selp*16 + c];
      int j = j0 + selp*16 + c;
      if (key > tk[7]) ins8_max(key, j, tk, tj);
    }
  }
  __syncthreads();                              // last select done; reuse keys[] as merge scratch
  float* ck = keys;                             // 2048 floats
  int*   cj = (int*)(keys + 2048);              // 2048 ints (fits: keys has 4160 slots)
#pragma unroll
  for (int m = 0; m < 8; ++m) { ck[selr*32 + selp*8 + m] = tk[m]; cj[selr*32 + selp*8 + m] = tj[m]; }
  __syncthreads();
  if (t < 64) {
    float bk[8]; int bj[8];
#pragma unroll
    for (int m = 0; m < 8; ++m) { bk[m] = -3.0e38f; bj[m] = 0x7fffffff; }
    for (int m = 0; m < 32; ++m) {
      float key = ck[t*32 + m]; int j = cj[t*32 + m];
      if (key > bk[7] || (key == bk[7] && j < bj[7])) ins8_maxtie(key, j, bk, bj);
    }
    int* o = idxo + ((size_t)b*NP + i0 + t) * 8;
#pragma unroll
    for (int m = 0; m < 8; ++m) o[m] = bj[m];
  }
}

// ---------------- edge MLP: h1=relu(P_i+Q_j) tile -> MFMA @ W2T -> bias/relu -> mean8 ----------------
__global__ __launch_bounds__(256) void edge_mlp_kernel(
    const float* __restrict__ P, const float* __restrict__ Q, const int* __restrict__ idx,
    const bf16_t* __restrict__ W2T, const float* __restrict__ b2,
    bf16_t* __restrict__ xout, float* __restrict__ pooled, int poolOff)
{
  __shared__ __align__(16) bf16_t At[128 * LDP];
  __shared__ float Mn[16 * 128];
  const int b = blockIdx.y, i0 = blockIdx.x * 16;
  const int t = threadIdx.x;
  {
    const int e = t >> 1, half = t & 1;         // 128 edge rows, 2 threads/row
    const int i = i0 + (e >> 3);
    const int j = idx[((size_t)b*NP + i)*8 + (e & 7)];
    const float4* Pr = (const float4*)(P + ((size_t)b*NP + i)*HD);
    const float4* Qr = (const float4*)(Q + ((size_t)b*NP + j)*HD);
#pragma unroll
    for (int c4 = half*16; c4 < half*16 + 16; ++c4) {
      float4 pv = Pr[c4], qv = Qr[c4];
      bf16x4 h;
      h[0] = (bf16_t)fmaxf(pv.x + qv.x, 0.f);
      h[1] = (bf16_t)fmaxf(pv.y + qv.y, 0.f);
      h[2] = (bf16_t)fmaxf(pv.z + qv.z, 0.f);
      h[3] = (bf16_t)fmaxf(pv.w + qv.w, 0.f);
      *(bf16x4*)&At[e*LDP + c4*4] = h;
    }
  }
  __syncthreads();
  const int lane = t & 63, w = t >> 6, quad = lane >> 4, l16 = lane & 15;
  f32x4 acc[2][8];
  f32x4 z = {0.f, 0.f, 0.f, 0.f};
#pragma unroll
  for (int rt = 0; rt < 2; ++rt)
#pragma unroll
    for (int ct = 0; ct < 8; ++ct) acc[rt][ct] = z;
#pragma unroll
  for (int ks = 0; ks < 4; ++ks) {
    const int kk = ks*32 + quad*8;
    bf16x8 a0 = *(const bf16x8*)&At[(w*32 + l16)*LDP + kk];
    bf16x8 a1 = *(const bf16x8*)&At[(w*32 + 16 + l16)*LDP + kk];
#pragma unroll
    for (int ct = 0; ct < 8; ++ct) {
      bf16x8 bb = *(const bf16x8*)&W2T[(ct*16 + l16)*HD + kk];
      acc[0][ct] = __builtin_amdgcn_mfma_f32_16x16x32_bf16(a0, bb, acc[0][ct], 0, 0, 0);
      acc[1][ct] = __builtin_amdgcn_mfma_f32_16x16x32_bf16(a1, bb, acc[1][ct], 0, 0, 0);
    }
  }
  // bias + relu + mean over 8 edge-rows (rows quad*4+r; quad-pair combine via shfl_xor 16)
#pragma unroll
  for (int rt = 0; rt < 2; ++rt)
#pragma unroll
    for (int ct = 0; ct < 8; ++ct) {
      float bv = b2[ct*16 + l16];
      float s = 0.f;
#pragma unroll
      for (int r = 0; r < 4; ++r) s += fmaxf(acc[rt][ct][r] + bv, 0.f);
      s += __shfl_xor(s, 16);
      if ((quad & 1) == 0) {
        int pt = w*4 + rt*2 + (quad >> 1);
        Mn[pt*128 + ct*16 + l16] = s * 0.125f;
      }
    }
  __syncthreads();
  for (int u = t; u < 2048; u += 256) {
    int pt = u >> 7, c = u & 127;
    xout[((size_t)b*NP + i0 + pt)*HD + c] = (bf16_t)Mn[u];
  }
  if (t < 128) {
    float ss = 0.f;
#pragma unroll
    for (int pt = 0; pt < 16; ++pt) ss += Mn[pt*128 + t];
    atomicAdd(&pooled[b*384 + poolOff + t], ss);
  }
}

// ---------------- final pooled MLP ----------------
__global__ __launch_bounds__(128) void final_mlp_kernel(
    const float* __restrict__ pooled, const float* __restrict__ W1, const float* __restrict__ b1v,
    const float* __restrict__ W2, const float* __restrict__ b2v, float* __restrict__ out)
{
  __shared__ float hb[128];
  int b = blockIdx.x, g = threadIdx.x;
  float h = b1v[g];
  const float inv = 1.0f / (float)NP;
  for (int c = 0; c < 384; ++c) h += pooled[b*384 + c] * inv * W1[c*128 + g];
  hb[g] = fmaxf(h, 0.f);
  __syncthreads();
  if (g < 2) {
    float o = b2v[g];
    for (int k2 = 0; k2 < 128; ++k2) o += hb[k2] * W2[k2*2 + g];
    out[b*2 + g] = o;
  }
}

extern "C" void kernel_launch(void* const* d_in, const int* in_sizes, int n_in,
                              void* d_out, int out_size, void* d_ws, size_t ws_size,
                              hipStream_t stream) {
  (void)in_sizes; (void)n_in; (void)out_size; (void)ws_size;
  const float* x    = (const float*)d_in[0];
  const float* c1W1 = (const float*)d_in[1];
  const float* c1b1 = (const float*)d_in[2];
  const float* c1W2 = (const float*)d_in[3];
  const float* c1b2 = (const float*)d_in[4];
  const float* c2W1 = (const float*)d_in[5];
  const float* c2b1 = (const float*)d_in[6];
  const float* c2W2 = (const float*)d_in[7];
  const float* c2b2 = (const float*)d_in[8];
  const float* c3W1 = (const float*)d_in[9];
  const float* c3b1 = (const float*)d_in[10];
  const float* c3W2 = (const float*)d_in[11];
  const float* c3b2 = (const float*)d_in[12];
  const float* mW1  = (const float*)d_in[13];
  const float* mb1  = (const float*)d_in[14];
  const float* mW2  = (const float*)d_in[15];
  const float* mb2  = (const float*)d_in[16];

  char* wsp = (char*)d_ws;
  auto carve = [&](size_t bytes) -> void* {
    void* p = (void*)wsp; wsp += (bytes + 255) & ~(size_t)255; return p;
  };
  bf16_t* x1b  = (bf16_t*)carve((size_t)NB*NP*HD*2);
  bf16_t* x2b  = (bf16_t*)carve((size_t)NB*NP*HD*2);
  bf16_t* x3b  = (bf16_t*)carve((size_t)NB*NP*HD*2);
  float*  Pbuf = (float*)carve((size_t)NB*NP*HD*4);
  float*  Qbuf = (float*)carve((size_t)NB*NP*HD*4);
  float*  sqb  = (float*)carve((size_t)NB*NP*4);
  int*    idxb = (int*)carve((size_t)NB*NP*8*4);
  bf16_t* W2T1 = (bf16_t*)carve(128*128*2);
  bf16_t* WpT2 = (bf16_t*)carve(128*128*2);
  bf16_t* WqT2 = (bf16_t*)carve(128*128*2);
  bf16_t* W2T2 = (bf16_t*)carve(128*128*2);
  bf16_t* WpT3 = (bf16_t*)carve(128*128*2);
  bf16_t* WqT3 = (bf16_t*)carve(128*128*2);
  bf16_t* W2T3 = (bf16_t*)carve(128*128*2);
  float*  pooled = (float*)carve((size_t)NB*384*4);

  hipMemsetAsync(pooled, 0, (size_t)NB*384*4, stream);
  wprep_kernel<<<448, 256, 0, stream>>>(c1W2, c2W1, c2W2, c3W1, c3W2,
                                        W2T1, WpT2, WqT2, W2T2, WpT3, WqT3, W2T3);
  // layer 1
  pq1_kernel<<<4096, 256, 0, stream>>>(x, c1W1, c1b1, Pbuf, Qbuf);
  knn1_kernel<<<dim3(NP/64, NB), 256, 0, stream>>>(x, idxb);
  edge_mlp_kernel<<<dim3(NP/16, NB), 256, 0, stream>>>(Pbuf, Qbuf, idxb, W2T1, c1b2, x1b, pooled, 0);
  // layer 2
  prep_sq_kernel<<<128, 256, 0, stream>>>(x1b, sqb);
  pq_gemm_kernel<<<dim3(NB*NP/128, 2), 256, 0, stream>>>(x1b, WpT2, WqT2, c2b1, Pbuf, Qbuf);
  knn_big_kernel<<<dim3(NP/64, NB), 256, 0, stream>>>(x1b, sqb, idxb);
  edge_mlp_kernel<<<dim3(NP/16, NB), 256, 0, stream>>>(Pbuf, Qbuf, idxb, W2T2, c2b2, x2b, pooled, 128);
  // layer 3
  prep_sq_kernel<<<128, 256, 0, stream>>>(x2b, sqb);
  pq_gemm_kernel<<<dim3(NB*NP/128, 2), 256, 0, stream>>>(x2b, WpT3, WqT3, c3b1, Pbuf, Qbuf);
  knn_big_kernel<<<dim3(NP/64, NB), 256, 0, stream>>>(x2b, sqb, idxb);
  edge_mlp_kernel<<<dim3(NP/16, NB), 256, 0, stream>>>(Pbuf, Qbuf, idxb, W2T3, c3b2, x3b, pooled, 256);
  // head
  final_mlp_kernel<<<NB, 128, 0, stream>>>(pooled, mW1, mb1, mW2, mb2, (float*)d_out);
}

// Round 3
// 1013.520 us; speedup vs baseline: 1.4409x; 1.1501x over previous
//
#include <hip/hip_runtime.h>

#define NB 16
#define NP 2048
#define HD 128
#define LDP 136   // padded LDS row (bf16 elems): 272B = 17*16B -> even bank spread for ds_read_b128

typedef __bf16 bf16_t;
typedef bf16_t bf16x8 __attribute__((ext_vector_type(8)));
typedef bf16_t bf16x4 __attribute__((ext_vector_type(4)));
typedef float  f32x4  __attribute__((ext_vector_type(4)));

// ---------------- top-8 insertion helpers (fully unrolled, register-resident) ----------------
__device__ __forceinline__ void ins8_min(float key, int j, float bd[8], int bi[8]) {
  float c = key; int cj = j;
#pragma unroll
  for (int m = 0; m < 8; ++m) {
    bool sm = c < bd[m];                 // strict: earlier j wins ties
    float tb = bd[m]; int ti = bi[m];
    if (sm) { bd[m] = c; bi[m] = cj; c = tb; cj = ti; }
  }
}

__device__ __forceinline__ void ins8_mintie(float key, int j, float bd[8], int bi[8]) {
  float c = key; int cj = j;
#pragma unroll
  for (int m = 0; m < 8; ++m) {
    bool sm = (c < bd[m]) || (c == bd[m] && cj < bi[m]);  // tie -> lower index (matches lax.top_k)
    float tb = bd[m]; int ti = bi[m];
    if (sm) { bd[m] = c; bi[m] = cj; c = tb; cj = ti; }
  }
}

__device__ __forceinline__ void ins8_max(float key, int j, float bd[8], int bi[8]) {
  float c = key; int cj = j;
#pragma unroll
  for (int m = 0; m < 8; ++m) {
    bool sm = c > bd[m];
    float tb = bd[m]; int ti = bi[m];
    if (sm) { bd[m] = c; bi[m] = cj; c = tb; cj = ti; }
  }
}

__device__ __forceinline__ void ins8_maxtie(float key, int j, float bd[8], int bi[8]) {
  float c = key; int cj = j;
#pragma unroll
  for (int m = 0; m < 8; ++m) {
    bool sm = (c > bd[m]) || (c == bd[m] && cj < bi[m]);  // tie -> lower index (matches lax.top_k)
    float tb = bd[m]; int ti = bi[m];
    if (sm) { bd[m] = c; bi[m] = cj; c = tb; cj = ti; }
  }
}

// ---------------- weight prep: build transposed bf16 weight mats ----------------
// m=0: W2T1  m=1: WpT2  m=2: WqT2  m=3: W2T2  m=4: WpT3  m=5: WqT3  m=6: W2T3
__global__ __launch_bounds__(256) void wprep_kernel(
    const float* __restrict__ c1W2, const float* __restrict__ c2W1, const float* __restrict__ c2W2,
    const float* __restrict__ c3W1, const float* __restrict__ c3W2,
    bf16_t* __restrict__ W2T1, bf16_t* __restrict__ WpT2, bf16_t* __restrict__ WqT2,
    bf16_t* __restrict__ W2T2, bf16_t* __restrict__ WpT3, bf16_t* __restrict__ WqT3,
    bf16_t* __restrict__ W2T3)
{
  int tid = blockIdx.x * 256 + threadIdx.x;     // < 7*16384
  int m = tid >> 14, e = tid & 16383;
  int r = e >> 7, c = e & 127;                  // out[r*128+c], r = out-channel (n), c = k/d
  switch (m) {
    case 0: W2T1[r*128+c] = (bf16_t)c1W2[c*128+r]; break;
    case 1: WpT2[r*128+c] = (bf16_t)(c2W1[c*128+r] - c2W1[(128+c)*128+r]); break;
    case 2: WqT2[r*128+c] = (bf16_t)c2W1[(128+c)*128+r]; break;
    case 3: W2T2[r*128+c] = (bf16_t)c2W2[c*128+r]; break;
    case 4: WpT3[r*128+c] = (bf16_t)(c3W1[c*128+r] - c3W1[(128+c)*128+r]); break;
    case 5: WqT3[r*128+c] = (bf16_t)c3W1[(128+c)*128+r]; break;
    case 6: W2T3[r*128+c] = (bf16_t)c3W2[c*128+r]; break;
  }
}

// ---------------- layer-1 P/Q (D=3, fp32 pointwise) ----------------
// P[i][c] = sum_d x_d*(W1[d][c]-W1[3+d][c]) + b1[c] ;  Q[j][c] = sum_d x_d*W1[3+d][c]
__global__ __launch_bounds__(256) void pq1_kernel(
    const float* __restrict__ x, const float* __restrict__ W1, const float* __restrict__ b1,
    float* __restrict__ P, float* __restrict__ Q)
{
  int tid = blockIdx.x * 256 + threadIdx.x;     // < 32768*32
  int row = tid >> 5, c0 = (tid & 31) * 4;
  float x0 = x[row*3+0], x1 = x[row*3+1], x2 = x[row*3+2];
#pragma unroll
  for (int u = 0; u < 4; ++u) {
    int c = c0 + u;
    float wq0 = W1[3*128+c], wq1 = W1[4*128+c], wq2 = W1[5*128+c];
    float wp0 = W1[0*128+c]-wq0, wp1 = W1[1*128+c]-wq1, wp2 = W1[2*128+c]-wq2;
    P[(size_t)row*HD + c] = x0*wp0 + x1*wp1 + x2*wp2 + b1[c];
    Q[(size_t)row*HD + c] = x0*wq0 + x1*wq1 + x2*wq2;
  }
}

// ---------------- kNN layer 1 (D=3, LDS-staged, 4 j-partitions per point) ----------------
// key_j = |xj|^2 - 2<xi,xj>  (monotone in d2; same formula as validated round-1 kernel)
__global__ __launch_bounds__(256) void knn1_kernel(const float* __restrict__ x, int* __restrict__ idxo)
{
  __shared__ __align__(16) float4 pts[NP];      // 32 KB: (x, y, z, |x|^2)
  __shared__ float ck[64 * 32];                 // 8 KB merge scratch
  __shared__ int   cjs[64 * 32];                // 8 KB
  const int b = blockIdx.y, i0 = blockIdx.x * 64;
  const int t = threadIdx.x;
  const float* __restrict__ xb = x + (size_t)b * NP * 3;
  for (int u = t; u < NP; u += 256) {
    float a0 = xb[u*3+0], a1 = xb[u*3+1], a2 = xb[u*3+2];
    pts[u] = make_float4(a0, a1, a2, a0*a0 + a1*a1 + a2*a2);
  }
  __syncthreads();
  const int selr = t >> 2, selp = t & 3;        // 64 rows x 4 partitions
  const float4 pi = pts[i0 + selr];
  float bd[8]; int bi[8];
#pragma unroll
  for (int m = 0; m < 8; ++m) { bd[m] = 3.0e38f; bi[m] = 0x7fffffff; }
  // interleaved partitions: j = 4*jj + selp -> the 4 lane addresses are contiguous
  // 16B blocks (conflict-free broadcast across the wave's 16 row-groups)
#pragma unroll 8
  for (int jj = 0; jj < NP / 4; ++jj) {
    int j = jj * 4 + selp;
    float4 p = pts[j];
    float key = p.w - 2.0f * (p.x*pi.x + p.y*pi.y + p.z*pi.z);
    if (key < bd[7]) ins8_min(key, j, bd, bi);
  }
#pragma unroll
  for (int m = 0; m < 8; ++m) { ck[selr*32 + selp*8 + m] = bd[m]; cjs[selr*32 + selp*8 + m] = bi[m]; }
  __syncthreads();
  if (t < 64) {
    float bk[8]; int bj[8];
#pragma unroll
    for (int m = 0; m < 8; ++m) { bk[m] = 3.0e38f; bj[m] = 0x7fffffff; }
    for (int m = 0; m < 32; ++m) {
      float key = ck[t*32 + m]; int j = cjs[t*32 + m];
      if (key < bk[7] || (key == bk[7] && j < bj[7])) ins8_mintie(key, j, bk, bj);
    }
    int* o = idxo + ((size_t)b*NP + i0 + t) * 8;
#pragma unroll
    for (int m = 0; m < 8; ++m) o[m] = bj[m];
  }
}

// ---------------- bf16 row norms ----------------
__global__ __launch_bounds__(256) void prep_sq_kernel(const bf16_t* __restrict__ X, float* __restrict__ sqg)
{
  int r = blockIdx.x * 256 + threadIdx.x;       // < 32768
  const bf16_t* row = X + (size_t)r * HD;
  float s = 0.f;
#pragma unroll
  for (int c = 0; c < HD; c += 8) {
    bf16x8 v = *(const bf16x8*)&row[c];
#pragma unroll
    for (int q = 0; q < 8; ++q) { float f = (float)v[q]; s += f * f; }
  }
  sqg[r] = s;
}

// ---------------- P/Q GEMM for layers 2/3: X(bf16)[32768x128] @ WT^T -> fp32 ----------------
__global__ __launch_bounds__(256) void pq_gemm_kernel(
    const bf16_t* __restrict__ X, const bf16_t* __restrict__ WpT, const bf16_t* __restrict__ WqT,
    const float* __restrict__ b1, float* __restrict__ P, float* __restrict__ Q)
{
  __shared__ __align__(16) bf16_t At[128 * LDP];
  const int r0 = blockIdx.x * 128;
  const bool isP = (blockIdx.y == 0);
  const bf16_t* __restrict__ WT = isP ? WpT : WqT;
  float* __restrict__ Out = isP ? P : Q;
  const int t = threadIdx.x;
  for (int u = t; u < 2048; u += 256) {
    int r = u >> 4, c = (u & 15) * 8;
    *(bf16x8*)&At[r*LDP + c] = *(const bf16x8*)&X[(size_t)(r0 + r)*HD + c];
  }
  __syncthreads();
  const int lane = t & 63, w = t >> 6, quad = lane >> 4, l16 = lane & 15;
  f32x4 acc[2][8];
  f32x4 z = {0.f, 0.f, 0.f, 0.f};
#pragma unroll
  for (int rt = 0; rt < 2; ++rt)
#pragma unroll
    for (int ct = 0; ct < 8; ++ct) acc[rt][ct] = z;
#pragma unroll
  for (int ks = 0; ks < 4; ++ks) {
    const int kk = ks*32 + quad*8;
    bf16x8 a0 = *(const bf16x8*)&At[(w*32 + l16)*LDP + kk];
    bf16x8 a1 = *(const bf16x8*)&At[(w*32 + 16 + l16)*LDP + kk];
#pragma unroll
    for (int ct = 0; ct < 8; ++ct) {
      bf16x8 bb = *(const bf16x8*)&WT[(ct*16 + l16)*HD + kk];   // L2-hot, 32KB matrix
      acc[0][ct] = __builtin_amdgcn_mfma_f32_16x16x32_bf16(a0, bb, acc[0][ct], 0, 0, 0);
      acc[1][ct] = __builtin_amdgcn_mfma_f32_16x16x32_bf16(a1, bb, acc[1][ct], 0, 0, 0);
    }
  }
#pragma unroll
  for (int rt = 0; rt < 2; ++rt)
#pragma unroll
    for (int ct = 0; ct < 8; ++ct) {
      float bv = isP ? b1[ct*16 + l16] : 0.f;
#pragma unroll
      for (int r = 0; r < 4; ++r) {
        int row = w*32 + rt*16 + quad*4 + r;
        Out[(size_t)(r0 + row)*HD + ct*16 + l16] = acc[rt][ct][r] + bv;
      }
    }
}

// ---------------- fused Gram(MFMA) + top-8 select for layers 2/3 ----------------
// Register-resident selection: no per-tile LDS, no main-loop barriers.
// Each thread owns 4 output rows (w*16+quad*4+r) and a fixed 16-way j-partition (l16).
// maximize key_j = 2*<xi,xj> - |xj|^2  (== sqi - d2, identical arithmetic to validated r1/r2 kernel)
__global__ __launch_bounds__(256) void knn_big_kernel(
    const bf16_t* __restrict__ X, const float* __restrict__ sqg, int* __restrict__ idxo)
{
  __shared__ __align__(16) float smem[8192];    // 32 KB keys / sq(first 2048 during main loop)
  __shared__ __align__(16) int   smi[8192];     // 32 KB idx
  const int b = blockIdx.y, i0 = blockIdx.x * 64;
  const int t = threadIdx.x;
  const bf16_t* __restrict__ Xb = X + (size_t)b * NP * HD;
  const float* __restrict__ sqb = sqg + (size_t)b * NP;
  for (int u = t; u < NP; u += 256) smem[u] = sqb[u];   // stage sq
  const int lane = t & 63, w = t >> 6, quad = lane >> 4, l16 = lane & 15;
  // A fragments direct from global (A[m=l16][k=quad*8+j], rows i0+w*16+l16)
  bf16x8 af[4];
#pragma unroll
  for (int ks = 0; ks < 4; ++ks)
    af[ks] = *(const bf16x8*)&Xb[(size_t)(i0 + w*16 + l16)*HD + ks*32 + quad*8];
  float tk[4][8]; int tj[4][8];
#pragma unroll
  for (int r = 0; r < 4; ++r)
#pragma unroll
    for (int m = 0; m < 8; ++m) { tk[r][m] = -3.0e38f; tj[r][m] = 0x7fffffff; }
  __syncthreads();
  f32x4 z = {0.f, 0.f, 0.f, 0.f};
  for (int jt = 0; jt < 32; ++jt) {
    const int j0 = jt * 64;
    f32x4 acc[4] = {z, z, z, z};
#pragma unroll
    for (int ks = 0; ks < 4; ++ks) {
      const int kk = ks*32 + quad*8;
#pragma unroll
      for (int ct = 0; ct < 4; ++ct) {
        // B[k][n]: n = candidate row j0+ct*16+l16, k = kk..kk+7  (L2-hot global)
        bf16x8 bb = *(const bf16x8*)&Xb[(size_t)(j0 + ct*16 + l16)*HD + kk];
        acc[ct] = __builtin_amdgcn_mfma_f32_16x16x32_bf16(af[ks], bb, acc[ct], 0, 0, 0);
      }
    }
#pragma unroll
    for (int ct = 0; ct < 4; ++ct) {
      const int j = j0 + ct*16 + l16;
      const float sqv = smem[j];                // broadcast LDS read
#pragma unroll
      for (int r = 0; r < 4; ++r) {
        float key = 2.f*acc[ct][r] - sqv;
        if (key > tk[r][7]) ins8_max(key, j, tk[r], tj[r]);  // ascending-j scan: strict > keeps lowest j on tie
      }
    }
  }
  __syncthreads();                              // sq no longer needed; smem/smi -> merge scratch
  // entry layout: slot = row*128 + part*8 + m   (row<64, part=l16<16)
  {
    const int row0 = w*16 + quad*4;
#pragma unroll
    for (int r = 0; r < 4; ++r) {
      int base = (row0 + r)*128 + l16*8;
#pragma unroll
      for (int m = 0; m < 8; ++m) { smem[base+m] = tk[r][m]; smi[base+m] = tj[r][m]; }
    }
  }
  __syncthreads();
  // stage 1: 4 threads per row; thread sp merges partitions sp*4..sp*4+3 (its exclusive 32-slot
  // region), writes its top-8 over the first 8 slots of that region (no cross-thread hazard)
  {
    const int row = t >> 2, sp = t & 3;
    const int base = row*128 + sp*32;
    float bk[8]; int bj[8];
#pragma unroll
    for (int m = 0; m < 8; ++m) { bk[m] = -3.0e38f; bj[m] = 0x7fffffff; }
    for (int m = 0; m < 32; ++m) {
      float key = smem[base+m]; int j = smi[base+m];
      if (key > bk[7] || (key == bk[7] && j < bj[7])) ins8_maxtie(key, j, bk, bj);
    }
#pragma unroll
    for (int m = 0; m < 8; ++m) { smem[base+m] = bk[m]; smi[base+m] = bj[m]; }
  }
  __syncthreads();
  // stage 2: one thread per row merges the 4 stage-1 lists
  if (t < 64) {
    float bk[8]; int bj[8];
#pragma unroll
    for (int m = 0; m < 8; ++m) { bk[m] = -3.0e38f; bj[m] = 0x7fffffff; }
#pragma unroll
    for (int sp = 0; sp < 4; ++sp) {
      const int base = t*128 + sp*32;
      for (int m = 0; m < 8; ++m) {
        float key = smem[base+m]; int j = smi[base+m];
        if (key > bk[7] || (key == bk[7] && j < bj[7])) ins8_maxtie(key, j, bk, bj);
      }
    }
    int* o = idxo + ((size_t)b*NP + i0 + t) * 8;
#pragma unroll
    for (int m = 0; m < 8; ++m) o[m] = bj[m];
  }
}

// ---------------- edge MLP: h1=relu(P_i+Q_j) tile -> MFMA @ W2T -> bias/relu -> mean8 ----------------
__global__ __launch_bounds__(256) void edge_mlp_kernel(
    const float* __restrict__ P, const float* __restrict__ Q, const int* __restrict__ idx,
    const bf16_t* __restrict__ W2T, const float* __restrict__ b2,
    bf16_t* __restrict__ xout, float* __restrict__ pooled, int poolOff)
{
  __shared__ __align__(16) bf16_t At[128 * LDP];
  __shared__ float Mn[16 * 128];
  const int b = blockIdx.y, i0 = blockIdx.x * 16;
  const int t = threadIdx.x;
  {
    const int e = t >> 1, half = t & 1;         // 128 edge rows, 2 threads/row
    const int i = i0 + (e >> 3);
    const int j = idx[((size_t)b*NP + i)*8 + (e & 7)];
    const float4* Pr = (const float4*)(P + ((size_t)b*NP + i)*HD);
    const float4* Qr = (const float4*)(Q + ((size_t)b*NP + j)*HD);
#pragma unroll
    for (int c4 = half*16; c4 < half*16 + 16; ++c4) {
      float4 pv = Pr[c4], qv = Qr[c4];
      bf16x4 h;
      h[0] = (bf16_t)fmaxf(pv.x + qv.x, 0.f);
      h[1] = (bf16_t)fmaxf(pv.y + qv.y, 0.f);
      h[2] = (bf16_t)fmaxf(pv.z + qv.z, 0.f);
      h[3] = (bf16_t)fmaxf(pv.w + qv.w, 0.f);
      *(bf16x4*)&At[e*LDP + c4*4] = h;
    }
  }
  __syncthreads();
  const int lane = t & 63, w = t >> 6, quad = lane >> 4, l16 = lane & 15;
  f32x4 acc[2][8];
  f32x4 z = {0.f, 0.f, 0.f, 0.f};
#pragma unroll
  for (int rt = 0; rt < 2; ++rt)
#pragma unroll
    for (int ct = 0; ct < 8; ++ct) acc[rt][ct] = z;
#pragma unroll
  for (int ks = 0; ks < 4; ++ks) {
    const int kk = ks*32 + quad*8;
    bf16x8 a0 = *(const bf16x8*)&At[(w*32 + l16)*LDP + kk];
    bf16x8 a1 = *(const bf16x8*)&At[(w*32 + 16 + l16)*LDP + kk];
#pragma unroll
    for (int ct = 0; ct < 8; ++ct) {
      bf16x8 bb = *(const bf16x8*)&W2T[(ct*16 + l16)*HD + kk];
      acc[0][ct] = __builtin_amdgcn_mfma_f32_16x16x32_bf16(a0, bb, acc[0][ct], 0, 0, 0);
      acc[1][ct] = __builtin_amdgcn_mfma_f32_16x16x32_bf16(a1, bb, acc[1][ct], 0, 0, 0);
    }
  }
  // bias + relu + mean over 8 edge-rows (rows quad*4+r; quad-pair combine via shfl_xor 16)
#pragma unroll
  for (int rt = 0; rt < 2; ++rt)
#pragma unroll
    for (int ct = 0; ct < 8; ++ct) {
      float bv = b2[ct*16 + l16];
      float s = 0.f;
#pragma unroll
      for (int r = 0; r < 4; ++r) s += fmaxf(acc[rt][ct][r] + bv, 0.f);
      s += __shfl_xor(s, 16);
      if ((quad & 1) == 0) {
        int pt = w*4 + rt*2 + (quad >> 1);
        Mn[pt*128 + ct*16 + l16] = s * 0.125f;
      }
    }
  __syncthreads();
  for (int u = t; u < 2048; u += 256) {
    int pt = u >> 7, c = u & 127;
    xout[((size_t)b*NP + i0 + pt)*HD + c] = (bf16_t)Mn[u];
  }
  if (t < 128) {
    float ss = 0.f;
#pragma unroll
    for (int pt = 0; pt < 16; ++pt) ss += Mn[pt*128 + t];
    atomicAdd(&pooled[b*384 + poolOff + t], ss);
  }
}

// ---------------- final pooled MLP ----------------
__global__ __launch_bounds__(128) void final_mlp_kernel(
    const float* __restrict__ pooled, const float* __restrict__ W1, const float* __restrict__ b1v,
    const float* __restrict__ W2, const float* __restrict__ b2v, float* __restrict__ out)
{
  __shared__ float hb[128];
  int b = blockIdx.x, g = threadIdx.x;
  float h = b1v[g];
  const float inv = 1.0f / (float)NP;
  for (int c = 0; c < 384; ++c) h += pooled[b*384 + c] * inv * W1[c*128 + g];
  hb[g] = fmaxf(h, 0.f);
  __syncthreads();
  if (g < 2) {
    float o = b2v[g];
    for (int k2 = 0; k2 < 128; ++k2) o += hb[k2] * W2[k2*2 + g];
    out[b*2 + g] = o;
  }
}

extern "C" void kernel_launch(void* const* d_in, const int* in_sizes, int n_in,
                              void* d_out, int out_size, void* d_ws, size_t ws_size,
                              hipStream_t stream) {
  (void)in_sizes; (void)n_in; (void)out_size; (void)ws_size;
  const float* x    = (const float*)d_in[0];
  const float* c1W1 = (const float*)d_in[1];
  const float* c1b1 = (const float*)d_in[2];
  const float* c1W2 = (const float*)d_in[3];
  const float* c1b2 = (const float*)d_in[4];
  const float* c2W1 = (const float*)d_in[5];
  const float* c2b1 = (const float*)d_in[6];
  const float* c2W2 = (const float*)d_in[7];
  const float* c2b2 = (const float*)d_in[8];
  const float* c3W1 = (const float*)d_in[9];
  const float* c3b1 = (const float*)d_in[10];
  const float* c3W2 = (const float*)d_in[11];
  const float* c3b2 = (const float*)d_in[12];
  const float* mW1  = (const float*)d_in[13];
  const float* mb1  = (const float*)d_in[14];
  const float* mW2  = (const float*)d_in[15];
  const float* mb2  = (const float*)d_in[16];

  char* wsp = (char*)d_ws;
  auto carve = [&](size_t bytes) -> void* {
    void* p = (void*)wsp; wsp += (bytes + 255) & ~(size_t)255; return p;
  };
  bf16_t* x1b  = (bf16_t*)carve((size_t)NB*NP*HD*2);
  bf16_t* x2b  = (bf16_t*)carve((size_t)NB*NP*HD*2);
  bf16_t* x3b  = (bf16_t*)carve((size_t)NB*NP*HD*2);
  float*  Pbuf = (float*)carve((size_t)NB*NP*HD*4);
  float*  Qbuf = (float*)carve((size_t)NB*NP*HD*4);
  float*  sqb  = (float*)carve((size_t)NB*NP*4);
  int*    idxb = (int*)carve((size_t)NB*NP*8*4);
  bf16_t* W2T1 = (bf16_t*)carve(128*128*2);
  bf16_t* WpT2 = (bf16_t*)carve(128*128*2);
  bf16_t* WqT2 = (bf16_t*)carve(128*128*2);
  bf16_t* W2T2 = (bf16_t*)carve(128*128*2);
  bf16_t* WpT3 = (bf16_t*)carve(128*128*2);
  bf16_t* WqT3 = (bf16_t*)carve(128*128*2);
  bf16_t* W2T3 = (bf16_t*)carve(128*128*2);
  float*  pooled = (float*)carve((size_t)NB*384*4);

  hipMemsetAsync(pooled, 0, (size_t)NB*384*4, stream);
  wprep_kernel<<<448, 256, 0, stream>>>(c1W2, c2W1, c2W2, c3W1, c3W2,
                                        W2T1, WpT2, WqT2, W2T2, WpT3, WqT3, W2T3);
  // layer 1
  pq1_kernel<<<4096, 256, 0, stream>>>(x, c1W1, c1b1, Pbuf, Qbuf);
  knn1_kernel<<<dim3(NP/64, NB), 256, 0, stream>>>(x, idxb);
  edge_mlp_kernel<<<dim3(NP/16, NB), 256, 0, stream>>>(Pbuf, Qbuf, idxb, W2T1, c1b2, x1b, pooled, 0);
  // layer 2
  prep_sq_kernel<<<128, 256, 0, stream>>>(x1b, sqb);
  pq_gemm_kernel<<<dim3(NB*NP/128, 2), 256, 0, stream>>>(x1b, WpT2, WqT2, c2b1, Pbuf, Qbuf);
  knn_big_kernel<<<dim3(NP/64, NB), 256, 0, stream>>>(x1b, sqb, idxb);
  edge_mlp_kernel<<<dim3(NP/16, NB), 256, 0, stream>>>(Pbuf, Qbuf, idxb, W2T2, c2b2, x2b, pooled, 128);
  // layer 3
  prep_sq_kernel<<<128, 256, 0, stream>>>(x2b, sqb);
  pq_gemm_kernel<<<dim3(NB*NP/128, 2), 256, 0, stream>>>(x2b, WpT3, WqT3, c3b1, Pbuf, Qbuf);
  knn_big_kernel<<<dim3(NP/64, NB), 256, 0, stream>>>(x2b, sqb, idxb);
  edge_mlp_kernel<<<dim3(NP/16, NB), 256, 0, stream>>>(Pbuf, Qbuf, idxb, W2T3, c3b2, x3b, pooled, 256);
  // head
  final_mlp_kernel<<<NB, 128, 0, stream>>>(pooled, mW1, mb1, mW2, mb2, (float*)d_out);
}

// Round 4
// 653.643 us; speedup vs baseline: 2.2342x; 1.5506x over previous
//
#include <hip/hip_runtime.h>

#define NB 16
#define NP 2048
#define HD 128
#define LDP 136   // padded LDS row (bf16 elems): 272B = 17*16B -> even bank spread for ds_read_b128

typedef __bf16 bf16_t;
typedef bf16_t bf16x8 __attribute__((ext_vector_type(8)));
typedef bf16_t bf16x4 __attribute__((ext_vector_type(4)));
typedef float  f32x4  __attribute__((ext_vector_type(4)));

// ---------------- packed-key top-8 machinery ----------------
// Named-scalar lists (NO arrays, NO address-taking -> guaranteed VGPRs).
// Key packing: fp32 -> sortable u32, truncate 11 mantissa LSBs, pack 11-bit index.
// MAX variant packs jrev=2047-j (tie -> lower j wins); MIN variant packs j directly.
__device__ __forceinline__ unsigned pk_max(float k, unsigned jrev) {
  unsigned u = __float_as_uint(k);
  unsigned s = u ^ (unsigned)(((int)u >> 31) | 0x80000000);
  return (s & 0xFFFFF800u) | jrev;
}
__device__ __forceinline__ unsigned pk_min(float k, unsigned j) {
  unsigned u = __float_as_uint(k);
  unsigned s = u ^ (unsigned)(((int)u >> 31) | 0x80000000);
  return (s & 0xFFFFF800u) | j;
}

#define T8_DECL_MAX(p) unsigned p##0=0u,p##1=0u,p##2=0u,p##3=0u,p##4=0u,p##5=0u,p##6=0u,p##7=0u
#define T8_STEP_MAX(b,cc) { unsigned t_ = ((b)<(cc)?(b):(cc)); (b) = ((b)>(cc)?(b):(cc)); (cc) = t_; }
#define T8_INS_MAX(p,c) { unsigned cc_=(c); \
  T8_STEP_MAX(p##0,cc_) T8_STEP_MAX(p##1,cc_) T8_STEP_MAX(p##2,cc_) T8_STEP_MAX(p##3,cc_) \
  T8_STEP_MAX(p##4,cc_) T8_STEP_MAX(p##5,cc_) T8_STEP_MAX(p##6,cc_) T8_STEP_MAX(p##7,cc_) }

#define T8_DECL_MIN(p) unsigned p##0=0xFFFFFFFFu,p##1=0xFFFFFFFFu,p##2=0xFFFFFFFFu,p##3=0xFFFFFFFFu,p##4=0xFFFFFFFFu,p##5=0xFFFFFFFFu,p##6=0xFFFFFFFFu,p##7=0xFFFFFFFFu
#define T8_STEP_MIN(b,cc) { unsigned t_ = ((b)>(cc)?(b):(cc)); (b) = ((b)<(cc)?(b):(cc)); (cc) = t_; }
#define T8_INS_MIN(p,c) { unsigned cc_=(c); \
  T8_STEP_MIN(p##0,cc_) T8_STEP_MIN(p##1,cc_) T8_STEP_MIN(p##2,cc_) T8_STEP_MIN(p##3,cc_) \
  T8_STEP_MIN(p##4,cc_) T8_STEP_MIN(p##5,cc_) T8_STEP_MIN(p##6,cc_) T8_STEP_MIN(p##7,cc_) }

// ---------------- weight prep: build transposed bf16 weight mats ----------------
// m=0: W2T1  m=1: WpT2  m=2: WqT2  m=3: W2T2  m=4: WpT3  m=5: WqT3  m=6: W2T3
__global__ __launch_bounds__(256) void wprep_kernel(
    const float* __restrict__ c1W2, const float* __restrict__ c2W1, const float* __restrict__ c2W2,
    const float* __restrict__ c3W1, const float* __restrict__ c3W2,
    bf16_t* __restrict__ W2T1, bf16_t* __restrict__ WpT2, bf16_t* __restrict__ WqT2,
    bf16_t* __restrict__ W2T2, bf16_t* __restrict__ WpT3, bf16_t* __restrict__ WqT3,
    bf16_t* __restrict__ W2T3)
{
  int tid = blockIdx.x * 256 + threadIdx.x;     // < 7*16384
  int m = tid >> 14, e = tid & 16383;
  int r = e >> 7, c = e & 127;                  // out[r*128+c], r = out-channel (n), c = k/d
  switch (m) {
    case 0: W2T1[r*128+c] = (bf16_t)c1W2[c*128+r]; break;
    case 1: WpT2[r*128+c] = (bf16_t)(c2W1[c*128+r] - c2W1[(128+c)*128+r]); break;
    case 2: WqT2[r*128+c] = (bf16_t)c2W1[(128+c)*128+r]; break;
    case 3: W2T2[r*128+c] = (bf16_t)c2W2[c*128+r]; break;
    case 4: WpT3[r*128+c] = (bf16_t)(c3W1[c*128+r] - c3W1[(128+c)*128+r]); break;
    case 5: WqT3[r*128+c] = (bf16_t)c3W1[(128+c)*128+r]; break;
    case 6: W2T3[r*128+c] = (bf16_t)c3W2[c*128+r]; break;
  }
}

// ---------------- layer-1 P/Q (D=3, fp32 pointwise) ----------------
__global__ __launch_bounds__(256) void pq1_kernel(
    const float* __restrict__ x, const float* __restrict__ W1, const float* __restrict__ b1,
    float* __restrict__ P, float* __restrict__ Q)
{
  int tid = blockIdx.x * 256 + threadIdx.x;     // < 32768*32
  int row = tid >> 5, c0 = (tid & 31) * 4;
  float x0 = x[row*3+0], x1 = x[row*3+1], x2 = x[row*3+2];
#pragma unroll
  for (int u = 0; u < 4; ++u) {
    int c = c0 + u;
    float wq0 = W1[3*128+c], wq1 = W1[4*128+c], wq2 = W1[5*128+c];
    float wp0 = W1[0*128+c]-wq0, wp1 = W1[1*128+c]-wq1, wp2 = W1[2*128+c]-wq2;
    P[(size_t)row*HD + c] = x0*wp0 + x1*wp1 + x2*wp2 + b1[c];
    Q[(size_t)row*HD + c] = x0*wq0 + x1*wq1 + x2*wq2;
  }
}

// ---------------- kNN layer 1 (D=3, LDS-staged, packed-key register top-8) ----------------
// key_j = |xj|^2 - 2<xi,xj>  (monotone in d2); MIN-select on packed u32
__global__ __launch_bounds__(256) void knn1_kernel(const float* __restrict__ x, int* __restrict__ idxo)
{
  __shared__ __align__(16) float4 pts[NP];      // 32 KB: (x, y, z, |x|^2)
  __shared__ unsigned mrg[64 * 32];             // 8 KB merge scratch (packed keys)
  const int b = blockIdx.y, i0 = blockIdx.x * 64;
  const int t = threadIdx.x;
  const float* __restrict__ xb = x + (size_t)b * NP * 3;
  for (int u = t; u < NP; u += 256) {
    float a0 = xb[u*3+0], a1 = xb[u*3+1], a2 = xb[u*3+2];
    pts[u] = make_float4(a0, a1, a2, a0*a0 + a1*a1 + a2*a2);
  }
  __syncthreads();
  const int selr = t >> 2, selp = t & 3;        // 64 rows x 4 partitions
  const float4 pi = pts[i0 + selr];
  T8_DECL_MIN(L);
#pragma unroll 4
  for (int jj = 0; jj < NP / 4; ++jj) {
    int j = jj * 4 + selp;
    float4 p = pts[j];
    float d  = p.x*pi.x + p.y*pi.y + p.z*pi.z;
    float key = p.w - 2.0f * d;
    T8_INS_MIN(L, pk_min(key, (unsigned)j));
  }
  {
    unsigned* e = &mrg[selr*32 + selp*8];
    e[0]=L0; e[1]=L1; e[2]=L2; e[3]=L3; e[4]=L4; e[5]=L5; e[6]=L6; e[7]=L7;
  }
  __syncthreads();
  if (t < 64) {
    T8_DECL_MIN(F);
    const unsigned* q = &mrg[t*32];
#pragma unroll
    for (int m = 0; m < 32; ++m) { unsigned v = q[m]; T8_INS_MIN(F, v); }
    int* o = idxo + ((size_t)b*NP + i0 + t) * 8;
    o[0] = (int)(F0 & 0x7FFu); o[1] = (int)(F1 & 0x7FFu);
    o[2] = (int)(F2 & 0x7FFu); o[3] = (int)(F3 & 0x7FFu);
    o[4] = (int)(F4 & 0x7FFu); o[5] = (int)(F5 & 0x7FFu);
    o[6] = (int)(F6 & 0x7FFu); o[7] = (int)(F7 & 0x7FFu);
  }
}

// ---------------- bf16 row norms ----------------
__global__ __launch_bounds__(256) void prep_sq_kernel(const bf16_t* __restrict__ X, float* __restrict__ sqg)
{
  int r = blockIdx.x * 256 + threadIdx.x;       // < 32768
  const bf16_t* row = X + (size_t)r * HD;
  float s = 0.f;
#pragma unroll
  for (int c = 0; c < HD; c += 8) {
    bf16x8 v = *(const bf16x8*)&row[c];
#pragma unroll
    for (int q = 0; q < 8; ++q) { float f = (float)v[q]; s += f * f; }
  }
  sqg[r] = s;
}

// ---------------- P/Q GEMM for layers 2/3: X(bf16)[32768x128] @ WT^T -> fp32 ----------------
__global__ __launch_bounds__(256) void pq_gemm_kernel(
    const bf16_t* __restrict__ X, const bf16_t* __restrict__ WpT, const bf16_t* __restrict__ WqT,
    const float* __restrict__ b1, float* __restrict__ P, float* __restrict__ Q)
{
  __shared__ __align__(16) bf16_t At[128 * LDP];
  const int r0 = blockIdx.x * 128;
  const bool isP = (blockIdx.y == 0);
  const bf16_t* __restrict__ WT = isP ? WpT : WqT;
  float* __restrict__ Out = isP ? P : Q;
  const int t = threadIdx.x;
  for (int u = t; u < 2048; u += 256) {
    int r = u >> 4, c = (u & 15) * 8;
    *(bf16x8*)&At[r*LDP + c] = *(const bf16x8*)&X[(size_t)(r0 + r)*HD + c];
  }
  __syncthreads();
  const int lane = t & 63, w = t >> 6, quad = lane >> 4, l16 = lane & 15;
  f32x4 acc[2][8];
  f32x4 z = {0.f, 0.f, 0.f, 0.f};
#pragma unroll
  for (int rt = 0; rt < 2; ++rt)
#pragma unroll
    for (int ct = 0; ct < 8; ++ct) acc[rt][ct] = z;
#pragma unroll
  for (int ks = 0; ks < 4; ++ks) {
    const int kk = ks*32 + quad*8;
    bf16x8 a0 = *(const bf16x8*)&At[(w*32 + l16)*LDP + kk];
    bf16x8 a1 = *(const bf16x8*)&At[(w*32 + 16 + l16)*LDP + kk];
#pragma unroll
    for (int ct = 0; ct < 8; ++ct) {
      bf16x8 bb = *(const bf16x8*)&WT[(ct*16 + l16)*HD + kk];   // L2-hot, 32KB matrix
      acc[0][ct] = __builtin_amdgcn_mfma_f32_16x16x32_bf16(a0, bb, acc[0][ct], 0, 0, 0);
      acc[1][ct] = __builtin_amdgcn_mfma_f32_16x16x32_bf16(a1, bb, acc[1][ct], 0, 0, 0);
    }
  }
#pragma unroll
  for (int rt = 0; rt < 2; ++rt)
#pragma unroll
    for (int ct = 0; ct < 8; ++ct) {
      float bv = isP ? b1[ct*16 + l16] : 0.f;
#pragma unroll
      for (int r = 0; r < 4; ++r) {
        int row = w*32 + rt*16 + quad*4 + r;
        Out[(size_t)(r0 + row)*HD + ct*16 + l16] = acc[rt][ct][r] + bv;
      }
    }
}

// ---------------- fused Gram(MFMA) + packed-key register top-8 for layers 2/3 ----------------
// maximize key_j = 2*<xi,xj> - |xj|^2. 4 row-lists per thread as named scalars.
__global__ __launch_bounds__(256) void knn_big_kernel(
    const bf16_t* __restrict__ X, const float* __restrict__ sqg, int* __restrict__ idxo)
{
  __shared__ __align__(16) unsigned sbuf[8192]; // 32 KB: sq (float bits) during main loop; merge scratch after
  const int b = blockIdx.y, i0 = blockIdx.x * 64;
  const int t = threadIdx.x;
  const bf16_t* __restrict__ Xb = X + (size_t)b * NP * HD;
  const float* __restrict__ sqb = sqg + (size_t)b * NP;
  for (int u = t; u < NP; u += 256) sbuf[u] = __float_as_uint(sqb[u]);
  const int lane = t & 63, w = t >> 6, quad = lane >> 4, l16 = lane & 15;
  const bf16_t* Ar = Xb + (size_t)(i0 + w*16 + l16)*HD + quad*8;
  bf16x8 af0 = *(const bf16x8*)(Ar);
  bf16x8 af1 = *(const bf16x8*)(Ar + 32);
  bf16x8 af2 = *(const bf16x8*)(Ar + 64);
  bf16x8 af3 = *(const bf16x8*)(Ar + 96);
  T8_DECL_MAX(Ra); T8_DECL_MAX(Rb); T8_DECL_MAX(Rc); T8_DECL_MAX(Rd);
  __syncthreads();
  const f32x4 z = {0.f, 0.f, 0.f, 0.f};
  const unsigned jrb = 2047u - (unsigned)l16;
  for (int jt = 0; jt < 32; ++jt) {
    const int j0 = jt * 64;
    const bf16_t* B0 = Xb + (size_t)(j0 + l16)*HD + quad*8;
    const bf16_t* B1 = B0 + 16*HD;
    const bf16_t* B2 = B0 + 32*HD;
    const bf16_t* B3 = B0 + 48*HD;
    f32x4 ac0 = z, ac1 = z, ac2 = z, ac3 = z;
    ac0 = __builtin_amdgcn_mfma_f32_16x16x32_bf16(af0, *(const bf16x8*)(B0     ), ac0, 0,0,0);
    ac1 = __builtin_amdgcn_mfma_f32_16x16x32_bf16(af0, *(const bf16x8*)(B1     ), ac1, 0,0,0);
    ac2 = __builtin_amdgcn_mfma_f32_16x16x32_bf16(af0, *(const bf16x8*)(B2     ), ac2, 0,0,0);
    ac3 = __builtin_amdgcn_mfma_f32_16x16x32_bf16(af0, *(const bf16x8*)(B3     ), ac3, 0,0,0);
    ac0 = __builtin_amdgcn_mfma_f32_16x16x32_bf16(af1, *(const bf16x8*)(B0 + 32), ac0, 0,0,0);
    ac1 = __builtin_amdgcn_mfma_f32_16x16x32_bf16(af1, *(const bf16x8*)(B1 + 32), ac1, 0,0,0);
    ac2 = __builtin_amdgcn_mfma_f32_16x16x32_bf16(af1, *(const bf16x8*)(B2 + 32), ac2, 0,0,0);
    ac3 = __builtin_amdgcn_mfma_f32_16x16x32_bf16(af1, *(const bf16x8*)(B3 + 32), ac3, 0,0,0);
    ac0 = __builtin_amdgcn_mfma_f32_16x16x32_bf16(af2, *(const bf16x8*)(B0 + 64), ac0, 0,0,0);
    ac1 = __builtin_amdgcn_mfma_f32_16x16x32_bf16(af2, *(const bf16x8*)(B1 + 64), ac1, 0,0,0);
    ac2 = __builtin_amdgcn_mfma_f32_16x16x32_bf16(af2, *(const bf16x8*)(B2 + 64), ac2, 0,0,0);
    ac3 = __builtin_amdgcn_mfma_f32_16x16x32_bf16(af2, *(const bf16x8*)(B3 + 64), ac3, 0,0,0);
    ac0 = __builtin_amdgcn_mfma_f32_16x16x32_bf16(af3, *(const bf16x8*)(B0 + 96), ac0, 0,0,0);
    ac1 = __builtin_amdgcn_mfma_f32_16x16x32_bf16(af3, *(const bf16x8*)(B1 + 96), ac1, 0,0,0);
    ac2 = __builtin_amdgcn_mfma_f32_16x16x32_bf16(af3, *(const bf16x8*)(B2 + 96), ac2, 0,0,0);
    ac3 = __builtin_amdgcn_mfma_f32_16x16x32_bf16(af3, *(const bf16x8*)(B3 + 96), ac3, 0,0,0);
    const float sq0 = __uint_as_float(sbuf[j0      + l16]);
    const float sq1 = __uint_as_float(sbuf[j0 + 16 + l16]);
    const float sq2 = __uint_as_float(sbuf[j0 + 32 + l16]);
    const float sq3 = __uint_as_float(sbuf[j0 + 48 + l16]);
    const unsigned jr0 = jrb - (unsigned)j0;
    const unsigned jr1 = jr0 - 16u, jr2 = jr0 - 32u, jr3 = jr0 - 48u;
    T8_INS_MAX(Ra, pk_max(__builtin_fmaf(2.f, ac0[0], -sq0), jr0));
    T8_INS_MAX(Rb, pk_max(__builtin_fmaf(2.f, ac0[1], -sq0), jr0));
    T8_INS_MAX(Rc, pk_max(__builtin_fmaf(2.f, ac0[2], -sq0), jr0));
    T8_INS_MAX(Rd, pk_max(__builtin_fmaf(2.f, ac0[3], -sq0), jr0));
    T8_INS_MAX(Ra, pk_max(__builtin_fmaf(2.f, ac1[0], -sq1), jr1));
    T8_INS_MAX(Rb, pk_max(__builtin_fmaf(2.f, ac1[1], -sq1), jr1));
    T8_INS_MAX(Rc, pk_max(__builtin_fmaf(2.f, ac1[2], -sq1), jr1));
    T8_INS_MAX(Rd, pk_max(__builtin_fmaf(2.f, ac1[3], -sq1), jr1));
    T8_INS_MAX(Ra, pk_max(__builtin_fmaf(2.f, ac2[0], -sq2), jr2));
    T8_INS_MAX(Rb, pk_max(__builtin_fmaf(2.f, ac2[1], -sq2), jr2));
    T8_INS_MAX(Rc, pk_max(__builtin_fmaf(2.f, ac2[2], -sq2), jr2));
    T8_INS_MAX(Rd, pk_max(__builtin_fmaf(2.f, ac2[3], -sq2), jr2));
    T8_INS_MAX(Ra, pk_max(__builtin_fmaf(2.f, ac3[0], -sq3), jr3));
    T8_INS_MAX(Rb, pk_max(__builtin_fmaf(2.f, ac3[1], -sq3), jr3));
    T8_INS_MAX(Rc, pk_max(__builtin_fmaf(2.f, ac3[2], -sq3), jr3));
    T8_INS_MAX(Rd, pk_max(__builtin_fmaf(2.f, ac3[3], -sq3), jr3));
  }
  __syncthreads();                              // sq no longer needed; sbuf -> merge scratch
  {
    const int row0 = w*16 + quad*4;
    unsigned* e = &sbuf[(row0+0)*128 + l16*8];
    e[0]=Ra0; e[1]=Ra1; e[2]=Ra2; e[3]=Ra3; e[4]=Ra4; e[5]=Ra5; e[6]=Ra6; e[7]=Ra7;
    e = &sbuf[(row0+1)*128 + l16*8];
    e[0]=Rb0; e[1]=Rb1; e[2]=Rb2; e[3]=Rb3; e[4]=Rb4; e[5]=Rb5; e[6]=Rb6; e[7]=Rb7;
    e = &sbuf[(row0+2)*128 + l16*8];
    e[0]=Rc0; e[1]=Rc1; e[2]=Rc2; e[3]=Rc3; e[4]=Rc4; e[5]=Rc5; e[6]=Rc6; e[7]=Rc7;
    e = &sbuf[(row0+3)*128 + l16*8];
    e[0]=Rd0; e[1]=Rd1; e[2]=Rd2; e[3]=Rd3; e[4]=Rd4; e[5]=Rd5; e[6]=Rd6; e[7]=Rd7;
  }
  __syncthreads();
  // stage 1: 4 threads/row, each merges its exclusive 4-partition (32-slot) region in place
  {
    const int row = t >> 2, sp = t & 3;
    unsigned* q = &sbuf[row*128 + sp*32];
    T8_DECL_MAX(S);
#pragma unroll
    for (int m = 0; m < 32; ++m) { unsigned v = q[m]; T8_INS_MAX(S, v); }
    q[0]=S0; q[1]=S1; q[2]=S2; q[3]=S3; q[4]=S4; q[5]=S5; q[6]=S6; q[7]=S7;
  }
  __syncthreads();
  // stage 2: one thread per row merges the 4 stage-1 lists, decodes indices
  if (t < 64) {
    T8_DECL_MAX(F);
    const unsigned* q = &sbuf[t*128];
#pragma unroll
    for (int sp = 0; sp < 4; ++sp)
#pragma unroll
      for (int m = 0; m < 8; ++m) { unsigned v = q[sp*32 + m]; T8_INS_MAX(F, v); }
    int* o = idxo + ((size_t)b*NP + i0 + t) * 8;
    o[0] = 2047 - (int)(F0 & 0x7FFu); o[1] = 2047 - (int)(F1 & 0x7FFu);
    o[2] = 2047 - (int)(F2 & 0x7FFu); o[3] = 2047 - (int)(F3 & 0x7FFu);
    o[4] = 2047 - (int)(F4 & 0x7FFu); o[5] = 2047 - (int)(F5 & 0x7FFu);
    o[6] = 2047 - (int)(F6 & 0x7FFu); o[7] = 2047 - (int)(F7 & 0x7FFu);
  }
}

// ---------------- edge MLP: h1=relu(P_i+Q_j) tile -> MFMA @ W2T -> bias/relu -> mean8 ----------------
__global__ __launch_bounds__(256) void edge_mlp_kernel(
    const float* __restrict__ P, const float* __restrict__ Q, const int* __restrict__ idx,
    const bf16_t* __restrict__ W2T, const float* __restrict__ b2,
    bf16_t* __restrict__ xout, float* __restrict__ pooled, int poolOff)
{
  __shared__ __align__(16) bf16_t At[128 * LDP];
  __shared__ float Mn[16 * 128];
  const int b = blockIdx.y, i0 = blockIdx.x * 16;
  const int t = threadIdx.x;
  {
    const int e = t >> 1, half = t & 1;         // 128 edge rows, 2 threads/row
    const int i = i0 + (e >> 3);
    const int j = idx[((size_t)b*NP + i)*8 + (e & 7)];
    const float4* Pr = (const float4*)(P + ((size_t)b*NP + i)*HD);
    const float4* Qr = (const float4*)(Q + ((size_t)b*NP + j)*HD);
#pragma unroll
    for (int c4 = half*16; c4 < half*16 + 16; ++c4) {
      float4 pv = Pr[c4], qv = Qr[c4];
      bf16x4 h;
      h[0] = (bf16_t)fmaxf(pv.x + qv.x, 0.f);
      h[1] = (bf16_t)fmaxf(pv.y + qv.y, 0.f);
      h[2] = (bf16_t)fmaxf(pv.z + qv.z, 0.f);
      h[3] = (bf16_t)fmaxf(pv.w + qv.w, 0.f);
      *(bf16x4*)&At[e*LDP + c4*4] = h;
    }
  }
  __syncthreads();
  const int lane = t & 63, w = t >> 6, quad = lane >> 4, l16 = lane & 15;
  f32x4 acc[2][8];
  f32x4 z = {0.f, 0.f, 0.f, 0.f};
#pragma unroll
  for (int rt = 0; rt < 2; ++rt)
#pragma unroll
    for (int ct = 0; ct < 8; ++ct) acc[rt][ct] = z;
#pragma unroll
  for (int ks = 0; ks < 4; ++ks) {
    const int kk = ks*32 + quad*8;
    bf16x8 a0 = *(const bf16x8*)&At[(w*32 + l16)*LDP + kk];
    bf16x8 a1 = *(const bf16x8*)&At[(w*32 + 16 + l16)*LDP + kk];
#pragma unroll
    for (int ct = 0; ct < 8; ++ct) {
      bf16x8 bb = *(const bf16x8*)&W2T[(ct*16 + l16)*HD + kk];
      acc[0][ct] = __builtin_amdgcn_mfma_f32_16x16x32_bf16(a0, bb, acc[0][ct], 0, 0, 0);
      acc[1][ct] = __builtin_amdgcn_mfma_f32_16x16x32_bf16(a1, bb, acc[1][ct], 0, 0, 0);
    }
  }
  // bias + relu + mean over 8 edge-rows (rows quad*4+r; quad-pair combine via shfl_xor 16)
#pragma unroll
  for (int rt = 0; rt < 2; ++rt)
#pragma unroll
    for (int ct = 0; ct < 8; ++ct) {
      float bv = b2[ct*16 + l16];
      float s = 0.f;
#pragma unroll
      for (int r = 0; r < 4; ++r) s += fmaxf(acc[rt][ct][r] + bv, 0.f);
      s += __shfl_xor(s, 16);
      if ((quad & 1) == 0) {
        int pt = w*4 + rt*2 + (quad >> 1);
        Mn[pt*128 + ct*16 + l16] = s * 0.125f;
      }
    }
  __syncthreads();
  for (int u = t; u < 2048; u += 256) {
    int pt = u >> 7, c = u & 127;
    xout[((size_t)b*NP + i0 + pt)*HD + c] = (bf16_t)Mn[u];
  }
  if (t < 128) {
    float ss = 0.f;
#pragma unroll
    for (int pt = 0; pt < 16; ++pt) ss += Mn[pt*128 + t];
    atomicAdd(&pooled[b*384 + poolOff + t], ss);
  }
}

// ---------------- final pooled MLP ----------------
__global__ __launch_bounds__(128) void final_mlp_kernel(
    const float* __restrict__ pooled, const float* __restrict__ W1, const float* __restrict__ b1v,
    const float* __restrict__ W2, const float* __restrict__ b2v, float* __restrict__ out)
{
  __shared__ float hb[128];
  int b = blockIdx.x, g = threadIdx.x;
  float h = b1v[g];
  const float inv = 1.0f / (float)NP;
  for (int c = 0; c < 384; ++c) h += pooled[b*384 + c] * inv * W1[c*128 + g];
  hb[g] = fmaxf(h, 0.f);
  __syncthreads();
  if (g < 2) {
    float o = b2v[g];
    for (int k2 = 0; k2 < 128; ++k2) o += hb[k2] * W2[k2*2 + g];
    out[b*2 + g] = o;
  }
}

extern "C" void kernel_launch(void* const* d_in, const int* in_sizes, int n_in,
                              void* d_out, int out_size, void* d_ws, size_t ws_size,
                              hipStream_t stream) {
  (void)in_sizes; (void)n_in; (void)out_size; (void)ws_size;
  const float* x    = (const float*)d_in[0];
  const float* c1W1 = (const float*)d_in[1];
  const float* c1b1 = (const float*)d_in[2];
  const float* c1W2 = (const float*)d_in[3];
  const float* c1b2 = (const float*)d_in[4];
  const float* c2W1 = (const float*)d_in[5];
  const float* c2b1 = (const float*)d_in[6];
  const float* c2W2 = (const float*)d_in[7];
  const float* c2b2 = (const float*)d_in[8];
  const float* c3W1 = (const float*)d_in[9];
  const float* c3b1 = (const float*)d_in[10];
  const float* c3W2 = (const float*)d_in[11];
  const float* c3b2 = (const float*)d_in[12];
  const float* mW1  = (const float*)d_in[13];
  const float* mb1  = (const float*)d_in[14];
  const float* mW2  = (const float*)d_in[15];
  const float* mb2  = (const float*)d_in[16];

  char* wsp = (char*)d_ws;
  auto carve = [&](size_t bytes) -> void* {
    void* p = (void*)wsp; wsp += (bytes + 255) & ~(size_t)255; return p;
  };
  bf16_t* x1b  = (bf16_t*)carve((size_t)NB*NP*HD*2);
  bf16_t* x2b  = (bf16_t*)carve((size_t)NB*NP*HD*2);
  bf16_t* x3b  = (bf16_t*)carve((size_t)NB*NP*HD*2);
  float*  Pbuf = (float*)carve((size_t)NB*NP*HD*4);
  float*  Qbuf = (float*)carve((size_t)NB*NP*HD*4);
  float*  sqb  = (float*)carve((size_t)NB*NP*4);
  int*    idxb = (int*)carve((size_t)NB*NP*8*4);
  bf16_t* W2T1 = (bf16_t*)carve(128*128*2);
  bf16_t* WpT2 = (bf16_t*)carve(128*128*2);
  bf16_t* WqT2 = (bf16_t*)carve(128*128*2);
  bf16_t* W2T2 = (bf16_t*)carve(128*128*2);
  bf16_t* WpT3 = (bf16_t*)carve(128*128*2);
  bf16_t* WqT3 = (bf16_t*)carve(128*128*2);
  bf16_t* W2T3 = (bf16_t*)carve(128*128*2);
  float*  pooled = (float*)carve((size_t)NB*384*4);

  hipMemsetAsync(pooled, 0, (size_t)NB*384*4, stream);
  wprep_kernel<<<448, 256, 0, stream>>>(c1W2, c2W1, c2W2, c3W1, c3W2,
                                        W2T1, WpT2, WqT2, W2T2, WpT3, WqT3, W2T3);
  // layer 1
  pq1_kernel<<<4096, 256, 0, stream>>>(x, c1W1, c1b1, Pbuf, Qbuf);
  knn1_kernel<<<dim3(NP/64, NB), 256, 0, stream>>>(x, idxb);
  edge_mlp_kernel<<<dim3(NP/16, NB), 256, 0, stream>>>(Pbuf, Qbuf, idxb, W2T1, c1b2, x1b, pooled, 0);
  // layer 2
  prep_sq_kernel<<<128, 256, 0, stream>>>(x1b, sqb);
  pq_gemm_kernel<<<dim3(NB*NP/128, 2), 256, 0, stream>>>(x1b, WpT2, WqT2, c2b1, Pbuf, Qbuf);
  knn_big_kernel<<<dim3(NP/64, NB), 256, 0, stream>>>(x1b, sqb, idxb);
  edge_mlp_kernel<<<dim3(NP/16, NB), 256, 0, stream>>>(Pbuf, Qbuf, idxb, W2T2, c2b2, x2b, pooled, 128);
  // layer 3
  prep_sq_kernel<<<128, 256, 0, stream>>>(x2b, sqb);
  pq_gemm_kernel<<<dim3(NB*NP/128, 2), 256, 0, stream>>>(x2b, WpT3, WqT3, c3b1, Pbuf, Qbuf);
  knn_big_kernel<<<dim3(NP/64, NB), 256, 0, stream>>>(x2b, sqb, idxb);
  edge_mlp_kernel<<<dim3(NP/16, NB), 256, 0, stream>>>(Pbuf, Qbuf, idxb, W2T3, c3b2, x3b, pooled, 256);
  // head
  final_mlp_kernel<<<NB, 128, 0, stream>>>(pooled, mW1, mb1, mW2, mb2, (float*)d_out);
}